// Round 3
// baseline (1185.280 us; speedup 1.0000x reference)
//
#include <hip/hip_runtime.h>
#include <hip/hip_bf16.h>

#define B_ 2
#define S_ 2048
#define D_ 2048
#define H_ 16
#define HD_ 128

typedef short s16x8 __attribute__((ext_vector_type(8)));
typedef float f32x4 __attribute__((ext_vector_type(4)));

__device__ inline unsigned short f2bf(float f) {
    __hip_bfloat16 h = __float2bfloat16(f);
    return __builtin_bit_cast(unsigned short, h);
}
__device__ inline float bf2f(unsigned short u) {
    __hip_bfloat16 h = __builtin_bit_cast(__hip_bfloat16, u);
    return __bfloat162float(h);
}

// ---------------- RoPE tables: cos/sin [S][64] fp32 ----------------
__global__ void rope_tab_k(float* __restrict__ cost, float* __restrict__ sint) {
    int s = blockIdx.x;
    int i = threadIdx.x;  // 0..63
    float inv = powf(10000.0f, -((float)(2 * i) / 128.0f));
    float ang = (float)s * inv;
    cost[s * 64 + i] = cosf(ang);
    sint[s * 64 + i] = sinf(ang);
}

// ---------------- GEMM: C[M][N] = A[M][K] * W[K][N] ----------------
// A is fp32 or bf16 (raw ushort); W is fp32 row-major (NOT transposed);
// C written bf16 or fp32. 128x128 tile, BK=64, 256 threads (4 waves 2x2).
template <bool A_BF16, bool OUT_BF16>
__global__ __launch_bounds__(256) void gemm_k(const void* __restrict__ Ap,
                                              const float* __restrict__ Bw,
                                              void* __restrict__ Cp,
                                              int M, int N, int K) {
    __shared__ unsigned short As[128][72];  // [m][k], pad to 72 (144B rows)
    __shared__ unsigned short Bs[128][72];  // [n][k] (transposed stage)
    int mbase = blockIdx.y * 128;
    int nbase = blockIdx.x * 128;
    int t = threadIdx.x;
    int w = t >> 6, lane = t & 63;
    int wr = w >> 1, wc = w & 1;
    int lr = lane >> 4, lc = lane & 15;

    f32x4 acc[4][4];
#pragma unroll
    for (int m = 0; m < 4; m++)
#pragma unroll
        for (int n = 0; n < 4; n++) acc[m][n] = f32x4{0.f, 0.f, 0.f, 0.f};

    for (int kb = 0; kb < K; kb += 64) {
        // ---- stage A tile [128][64] ----
        {
            int row = t >> 1;
            int kh = (t & 1) * 32;
            if constexpr (A_BF16) {
                const unsigned short* A =
                    (const unsigned short*)Ap + (size_t)(mbase + row) * K + kb + kh;
#pragma unroll
                for (int q = 0; q < 4; q++) {
                    s16x8 v = *(const s16x8*)(A + q * 8);
                    *(s16x8*)&As[row][kh + q * 8] = v;
                }
            } else {
                const float* A = (const float*)Ap + (size_t)(mbase + row) * K + kb + kh;
#pragma unroll
                for (int q = 0; q < 8; q++) {
                    float4 v = *(const float4*)(A + q * 4);
                    ushort4 o;
                    o.x = f2bf(v.x); o.y = f2bf(v.y); o.z = f2bf(v.z); o.w = f2bf(v.w);
                    *(ushort4*)&As[row][kh + q * 4] = o;
                }
            }
        }
        // ---- stage B tile with transpose: Bs[n][k] = W[kb+k][nbase+n] ----
        {
            int kk = t >> 2;           // 0..63
            int n0 = (t & 3) * 32;     // 0,32,64,96
            const float* Bp2 = Bw + (size_t)(kb + kk) * N + nbase + n0;
#pragma unroll
            for (int q = 0; q < 8; q++) {
                float4 v = *(const float4*)(Bp2 + q * 4);
                Bs[n0 + q * 4 + 0][kk] = f2bf(v.x);
                Bs[n0 + q * 4 + 1][kk] = f2bf(v.y);
                Bs[n0 + q * 4 + 2][kk] = f2bf(v.z);
                Bs[n0 + q * 4 + 3][kk] = f2bf(v.w);
            }
        }
        __syncthreads();
        // ---- compute ----
#pragma unroll
        for (int kc = 0; kc < 2; kc++) {
            int ko = kc * 32 + lr * 8;
            s16x8 af[4], bfr[4];
#pragma unroll
            for (int m = 0; m < 4; m++)
                af[m] = *(const s16x8*)&As[wr * 64 + m * 16 + lc][ko];
#pragma unroll
            for (int n = 0; n < 4; n++)
                bfr[n] = *(const s16x8*)&Bs[wc * 64 + n * 16 + lc][ko];
#pragma unroll
            for (int m = 0; m < 4; m++)
#pragma unroll
                for (int n = 0; n < 4; n++)
                    acc[m][n] = __builtin_amdgcn_mfma_f32_16x16x32_bf16(
                        af[m], bfr[n], acc[m][n], 0, 0, 0);
        }
        __syncthreads();
    }
    // ---- epilogue ----
    int rbase = mbase + wr * 64;
    int cbase = nbase + wc * 64;
#pragma unroll
    for (int m = 0; m < 4; m++)
#pragma unroll
        for (int n = 0; n < 4; n++)
#pragma unroll
            for (int r = 0; r < 4; r++) {
                int row = rbase + m * 16 + lr * 4 + r;
                int col = cbase + n * 16 + lc;
                float v = acc[m][n][r];
                if constexpr (OUT_BF16)
                    ((unsigned short*)Cp)[(size_t)row * N + col] = f2bf(v);
                else
                    ((float*)Cp)[(size_t)row * N + col] = v;
            }
}

// ---------------- RoPE + reshape to [B,H,S,HD] for Q and K ----------------
__global__ void rope_qk_k(const unsigned short* __restrict__ qtmp,
                          const unsigned short* __restrict__ ktmp,
                          const float* __restrict__ cost, const float* __restrict__ sint,
                          const int* __restrict__ pos_ids,
                          unsigned short* __restrict__ Qr, unsigned short* __restrict__ Kr) {
    int s = blockIdx.x;
    int bh = blockIdx.y;
    int b = bh >> 4, h = bh & 15;
    int d = threadIdx.x;  // 0..63
    int pos = pos_ids[(size_t)b * S_ + s];
    float c = cost[pos * 64 + d];
    float sn = sint[pos * 64 + d];
    size_t src = ((size_t)(b * S_ + s)) * D_ + h * HD_ + d;
    float q1 = bf2f(qtmp[src]), q2 = bf2f(qtmp[src + 64]);
    float k1 = bf2f(ktmp[src]), k2 = bf2f(ktmp[src + 64]);
    size_t dst = ((size_t)bh * S_ + s) * HD_ + d;
    Qr[dst] = f2bf(q1 * c - q2 * sn);
    Qr[dst + 64] = f2bf(q2 * c + q1 * sn);
    Kr[dst] = f2bf(k1 * c - k2 * sn);
    Kr[dst + 64] = f2bf(k2 * c + k1 * sn);
}

// ---------------- V transpose: Vt[B,H,HD,S] = V[B,S,H,HD] ----------------
__global__ __launch_bounds__(256) void vtrans_k(const unsigned short* __restrict__ vtmp,
                                                unsigned short* __restrict__ Vt) {
    __shared__ unsigned short tile[64][65];
    int sb = blockIdx.x * 64;
    int db = blockIdx.y * 64;  // 0 or 64
    int bh = blockIdx.z;
    int b = bh >> 4, h = bh & 15;
    int t = threadIdx.x;
    int c = t & 63, r4 = t >> 6;
#pragma unroll
    for (int i = 0; i < 16; i++) {
        int r = r4 * 16 + i;
        tile[r][c] = vtmp[((size_t)(b * S_ + sb + r)) * D_ + h * HD_ + db + c];
    }
    __syncthreads();
#pragma unroll
    for (int i = 0; i < 16; i++) {
        int dr = r4 * 16 + i;
        Vt[((size_t)bh * HD_ + db + dr) * S_ + sb + c] = tile[c][dr];
    }
}

// ---------------- Flash attention (causal) ----------------
// 4 independent waves per 256-thread block; each wave owns one 16-row q-tile
// with a private LDS P-buffer (no __syncthreads — divergent per-wave trip
// counts are safe). q-tiles mapped longest-first to fix causal load imbalance.
__global__ __launch_bounds__(256) void attn_k(const unsigned short* __restrict__ Qr,
                                              const unsigned short* __restrict__ Kr,
                                              const unsigned short* __restrict__ Vt,
                                              unsigned short* __restrict__ attnout) {
    __shared__ unsigned short P[4][16][32];  // per-wave transpose buffer
    int w = threadIdx.x >> 6;
    int lane = threadIdx.x & 63;
    int lr = lane >> 4, lc = lane & 15;
    int bh = blockIdx.y;
    int b = bh >> 4, h = bh & 15;
    int gw = blockIdx.x * 4 + w;          // 0..127
    int qt = (S_ / 16 - 1) - gw;          // longest q-tiles launch first
    int qbase = qt * 16;
    const unsigned short* Qb = Qr + ((size_t)bh * S_ + qbase) * HD_;
    const unsigned short* Kb = Kr + ((size_t)bh * S_) * HD_;
    const unsigned short* Vb = Vt + ((size_t)bh * HD_) * S_;

    s16x8 aq[4];
#pragma unroll
    for (int kc = 0; kc < 4; kc++)
        aq[kc] = *(const s16x8*)(Qb + (size_t)lc * HD_ + kc * 32 + lr * 8);

    float mrow[4], lsum[4];
    f32x4 o[8];
#pragma unroll
    for (int r = 0; r < 4; r++) { mrow[r] = -1e30f; lsum[r] = 0.f; }
#pragma unroll
    for (int dc = 0; dc < 8; dc++) o[dc] = f32x4{0.f, 0.f, 0.f, 0.f};

    int nkt = (qbase + 16 + 31) >> 5;
    const float scale = 0.088388347648318447f;  // 1/sqrt(128)

    for (int kt = 0; kt < nkt; kt++) {
        int kb = kt * 32;
        f32x4 sf[2];
#pragma unroll
        for (int ct = 0; ct < 2; ct++) {
            f32x4 s4 = f32x4{0.f, 0.f, 0.f, 0.f};
            const unsigned short* Kp = Kb + (size_t)(kb + ct * 16 + lc) * HD_ + lr * 8;
            __builtin_amdgcn_s_setprio(1);
#pragma unroll
            for (int kc = 0; kc < 4; kc++) {
                s16x8 bk = *(const s16x8*)(Kp + kc * 32);
                s4 = __builtin_amdgcn_mfma_f32_16x16x32_bf16(aq[kc], bk, s4, 0, 0, 0);
            }
            __builtin_amdgcn_s_setprio(0);
            sf[ct] = s4;
        }
        // scale + causal mask
#pragma unroll
        for (int ct = 0; ct < 2; ct++) {
            int key = kb + ct * 16 + lc;
#pragma unroll
            for (int r = 0; r < 4; r++) {
                int qr = qbase + lr * 4 + r;
                float v = sf[ct][r] * scale;
                sf[ct][r] = (key <= qr) ? v : -1e30f;
            }
        }
        // row max across the 16 lanes of each row-group
        float tmax[4];
#pragma unroll
        for (int r = 0; r < 4; r++) tmax[r] = fmaxf(sf[0][r], sf[1][r]);
#pragma unroll
        for (int off = 1; off < 16; off <<= 1)
#pragma unroll
            for (int r = 0; r < 4; r++)
                tmax[r] = fmaxf(tmax[r], __shfl_xor(tmax[r], off, 64));
        float alpha[4];
#pragma unroll
        for (int r = 0; r < 4; r++) {
            float nm = fmaxf(mrow[r], tmax[r]);
            alpha[r] = __expf(mrow[r] - nm);
            mrow[r] = nm;
        }
        float psum[4] = {0.f, 0.f, 0.f, 0.f};
#pragma unroll
        for (int ct = 0; ct < 2; ct++)
#pragma unroll
            for (int r = 0; r < 4; r++) {
                float p = __expf(sf[ct][r] - mrow[r]);
                sf[ct][r] = p;
                psum[r] += p;
            }
#pragma unroll
        for (int off = 1; off < 16; off <<= 1)
#pragma unroll
            for (int r = 0; r < 4; r++) psum[r] += __shfl_xor(psum[r], off, 64);
#pragma unroll
        for (int r = 0; r < 4; r++) lsum[r] = lsum[r] * alpha[r] + psum[r];
#pragma unroll
        for (int dc = 0; dc < 8; dc++)
#pragma unroll
            for (int r = 0; r < 4; r++) o[dc][r] *= alpha[r];
        // P (D-layout) -> LDS -> A-frag layout (per-wave buffer, wave-local dep)
#pragma unroll
        for (int ct = 0; ct < 2; ct++)
#pragma unroll
            for (int r = 0; r < 4; r++) P[w][lr * 4 + r][ct * 16 + lc] = f2bf(sf[ct][r]);
        s16x8 pa = *(const s16x8*)&P[w][lc][lr * 8];
        // PV: o[dc] += P(16x32) * V(32x16 per d-chunk)
        __builtin_amdgcn_s_setprio(1);
#pragma unroll
        for (int dc = 0; dc < 8; dc++) {
            const unsigned short* Vp = Vb + (size_t)(dc * 16 + lc) * S_ + kb + lr * 8;
            s16x8 bv = *(const s16x8*)Vp;
            o[dc] = __builtin_amdgcn_mfma_f32_16x16x32_bf16(pa, bv, o[dc], 0, 0, 0);
        }
        __builtin_amdgcn_s_setprio(0);
    }
    // epilogue: attnout[b*S+row][h*HD+col] bf16
#pragma unroll
    for (int dc = 0; dc < 8; dc++)
#pragma unroll
        for (int r = 0; r < 4; r++) {
            int row = qbase + lr * 4 + r;
            int col = h * HD_ + dc * 16 + lc;
            float v = o[dc][r] / lsum[r];
            attnout[((size_t)(b * S_ + row)) * D_ + col] = f2bf(v);
        }
}

extern "C" void kernel_launch(void* const* d_in, const int* in_sizes, int n_in,
                              void* d_out, int out_size, void* d_ws, size_t ws_size,
                              hipStream_t stream) {
    const float* hidden = (const float*)d_in[0];
    // d_in[1]: attention_mask (pure causal; implemented analytically)
    const int* pos_ids = (const int*)d_in[2];  // integer inputs arrive as int32
    const float* Wq = (const float*)d_in[3];
    const float* Wk = (const float*)d_in[4];
    const float* Wv = (const float*)d_in[5];
    const float* Wo = (const float*)d_in[6];
    float* out = (float*)d_out;

    char* ws = (char*)d_ws;
    const size_t MK = (size_t)B_ * S_ * D_;  // 8M elements
    float* cost = (float*)ws;                            // 512KB
    float* sint = (float*)(ws + 524288);                 // 512KB
    unsigned short* qtmp = (unsigned short*)(ws + 1048576);
    unsigned short* ktmp = qtmp + MK;
    unsigned short* vtmp = ktmp + MK;
    unsigned short* Qr = vtmp + MK;
    unsigned short* Kr = Qr + MK;
    unsigned short* Vt = Kr + MK;
    unsigned short* attnout = qtmp;  // reuse (qtmp dead after rope_qk_k)

    const int M = B_ * S_;  // 4096
    dim3 ggrid(D_ / 128, M / 128);  // (16, 32)

    rope_tab_k<<<S_, 64, 0, stream>>>(cost, sint);
    gemm_k<false, true><<<ggrid, 256, 0, stream>>>(hidden, Wq, qtmp, M, D_, D_);
    gemm_k<false, true><<<ggrid, 256, 0, stream>>>(hidden, Wk, ktmp, M, D_, D_);
    gemm_k<false, true><<<ggrid, 256, 0, stream>>>(hidden, Wv, vtmp, M, D_, D_);
    rope_qk_k<<<dim3(S_, B_ * H_), 64, 0, stream>>>(qtmp, ktmp, cost, sint, pos_ids, Qr, Kr);
    vtrans_k<<<dim3(S_ / 64, HD_ / 64, B_ * H_), 256, 0, stream>>>(vtmp, Vt);
    attn_k<<<dim3(S_ / 16 / 4, B_ * H_), 256, 0, stream>>>(Qr, Kr, Vt, attnout);
    gemm_k<true, false><<<ggrid, 256, 0, stream>>>(attnout, Wo, out, M, D_, D_);
}

// Round 4
// 901.837 us; speedup vs baseline: 1.3143x; 1.3143x over previous
//
#include <hip/hip_runtime.h>
#include <hip/hip_bf16.h>

#define B_ 2
#define S_ 2048
#define D_ 2048
#define H_ 16
#define HD_ 128

typedef short s16x8 __attribute__((ext_vector_type(8)));
typedef float f32x4 __attribute__((ext_vector_type(4)));

#define AS1 __attribute__((address_space(1)))
#define AS3 __attribute__((address_space(3)))

__device__ __forceinline__ void gl_lds16(const void* g, void* l) {
    __builtin_amdgcn_global_load_lds((AS1 const unsigned int*)g, (AS3 unsigned int*)l, 16, 0, 0);
}

__device__ inline unsigned short f2bf(float f) {
    __hip_bfloat16 h = __float2bfloat16(f);
    return __builtin_bit_cast(unsigned short, h);
}
__device__ inline float bf2f(unsigned short u) {
    __hip_bfloat16 h = __builtin_bit_cast(__hip_bfloat16, u);
    return __bfloat162float(h);
}

// ---------------- RoPE tables: cos/sin [S][64] fp32 ----------------
__global__ void rope_tab_k(float* __restrict__ cost, float* __restrict__ sint) {
    int s = blockIdx.x;
    int i = threadIdx.x;  // 0..63
    float inv = powf(10000.0f, -((float)(2 * i) / 128.0f));
    float ang = (float)s * inv;
    cost[s * 64 + i] = cosf(ang);
    sint[s * 64 + i] = sinf(ang);
}

// ---------------- GEMM: C[M][N] = A[M][K] * W[K][N] ----------------
template <bool A_BF16, bool OUT_BF16>
__global__ __launch_bounds__(256) void gemm_k(const void* __restrict__ Ap,
                                              const float* __restrict__ Bw,
                                              void* __restrict__ Cp,
                                              int M, int N, int K) {
    __shared__ unsigned short As[128][72];  // [m][k], pad to 72 (144B rows)
    __shared__ unsigned short Bs[128][72];  // [n][k] (transposed stage)
    int mbase = blockIdx.y * 128;
    int nbase = blockIdx.x * 128;
    int t = threadIdx.x;
    int w = t >> 6, lane = t & 63;
    int wr = w >> 1, wc = w & 1;
    int lr = lane >> 4, lc = lane & 15;

    f32x4 acc[4][4];
#pragma unroll
    for (int m = 0; m < 4; m++)
#pragma unroll
        for (int n = 0; n < 4; n++) acc[m][n] = f32x4{0.f, 0.f, 0.f, 0.f};

    for (int kb = 0; kb < K; kb += 64) {
        // ---- stage A tile [128][64] ----
        {
            int row = t >> 1;
            int kh = (t & 1) * 32;
            if constexpr (A_BF16) {
                const unsigned short* A =
                    (const unsigned short*)Ap + (size_t)(mbase + row) * K + kb + kh;
#pragma unroll
                for (int q = 0; q < 4; q++) {
                    s16x8 v = *(const s16x8*)(A + q * 8);
                    *(s16x8*)&As[row][kh + q * 8] = v;
                }
            } else {
                const float* A = (const float*)Ap + (size_t)(mbase + row) * K + kb + kh;
#pragma unroll
                for (int q = 0; q < 8; q++) {
                    float4 v = *(const float4*)(A + q * 4);
                    ushort4 o;
                    o.x = f2bf(v.x); o.y = f2bf(v.y); o.z = f2bf(v.z); o.w = f2bf(v.w);
                    *(ushort4*)&As[row][kh + q * 4] = o;
                }
            }
        }
        // ---- stage B tile with transpose: Bs[n][k] = W[kb+k][nbase+n] ----
        {
            int kk = t >> 2;           // 0..63
            int n0 = (t & 3) * 32;     // 0,32,64,96
            const float* Bp2 = Bw + (size_t)(kb + kk) * N + nbase + n0;
#pragma unroll
            for (int q = 0; q < 8; q++) {
                float4 v = *(const float4*)(Bp2 + q * 4);
                Bs[n0 + q * 4 + 0][kk] = f2bf(v.x);
                Bs[n0 + q * 4 + 1][kk] = f2bf(v.y);
                Bs[n0 + q * 4 + 2][kk] = f2bf(v.z);
                Bs[n0 + q * 4 + 3][kk] = f2bf(v.w);
            }
        }
        __syncthreads();
        // ---- compute ----
#pragma unroll
        for (int kc = 0; kc < 2; kc++) {
            int ko = kc * 32 + lr * 8;
            s16x8 af[4], bfr[4];
#pragma unroll
            for (int m = 0; m < 4; m++)
                af[m] = *(const s16x8*)&As[wr * 64 + m * 16 + lc][ko];
#pragma unroll
            for (int n = 0; n < 4; n++)
                bfr[n] = *(const s16x8*)&Bs[wc * 64 + n * 16 + lc][ko];
#pragma unroll
            for (int m = 0; m < 4; m++)
#pragma unroll
                for (int n = 0; n < 4; n++)
                    acc[m][n] = __builtin_amdgcn_mfma_f32_16x16x32_bf16(
                        af[m], bfr[n], acc[m][n], 0, 0, 0);
        }
        __syncthreads();
    }
    // ---- epilogue ----
    int rbase = mbase + wr * 64;
    int cbase = nbase + wc * 64;
#pragma unroll
    for (int m = 0; m < 4; m++)
#pragma unroll
        for (int n = 0; n < 4; n++)
#pragma unroll
            for (int r = 0; r < 4; r++) {
                int row = rbase + m * 16 + lr * 4 + r;
                int col = cbase + n * 16 + lc;
                float v = acc[m][n][r];
                if constexpr (OUT_BF16)
                    ((unsigned short*)Cp)[(size_t)row * N + col] = f2bf(v);
                else
                    ((float*)Cp)[(size_t)row * N + col] = v;
            }
}

// ---------------- RoPE + reshape to [B,H,S,HD] for Q and K ----------------
__global__ void rope_qk_k(const unsigned short* __restrict__ qtmp,
                          const unsigned short* __restrict__ ktmp,
                          const float* __restrict__ cost, const float* __restrict__ sint,
                          const int* __restrict__ pos_ids,
                          unsigned short* __restrict__ Qr, unsigned short* __restrict__ Kr) {
    int s = blockIdx.x;
    int bh = blockIdx.y;
    int b = bh >> 4, h = bh & 15;
    int d = threadIdx.x;  // 0..63
    int pos = pos_ids[(size_t)b * S_ + s];
    float c = cost[pos * 64 + d];
    float sn = sint[pos * 64 + d];
    size_t src = ((size_t)(b * S_ + s)) * D_ + h * HD_ + d;
    float q1 = bf2f(qtmp[src]), q2 = bf2f(qtmp[src + 64]);
    float k1 = bf2f(ktmp[src]), k2 = bf2f(ktmp[src + 64]);
    size_t dst = ((size_t)bh * S_ + s) * HD_ + d;
    Qr[dst] = f2bf(q1 * c - q2 * sn);
    Qr[dst + 64] = f2bf(q2 * c + q1 * sn);
    Kr[dst] = f2bf(k1 * c - k2 * sn);
    Kr[dst + 64] = f2bf(k2 * c + k1 * sn);
}

// ---------------- V transpose: Vt[B,H,HD,S] = V[B,S,H,HD] ----------------
__global__ __launch_bounds__(256) void vtrans_k(const unsigned short* __restrict__ vtmp,
                                                unsigned short* __restrict__ Vt) {
    __shared__ unsigned short tile[64][65];
    int sb = blockIdx.x * 64;
    int db = blockIdx.y * 64;  // 0 or 64
    int bh = blockIdx.z;
    int b = bh >> 4, h = bh & 15;
    int t = threadIdx.x;
    int c = t & 63, r4 = t >> 6;
#pragma unroll
    for (int i = 0; i < 16; i++) {
        int r = r4 * 16 + i;
        tile[r][c] = vtmp[((size_t)(b * S_ + sb + r)) * D_ + h * HD_ + db + c];
    }
    __syncthreads();
#pragma unroll
    for (int i = 0; i < 16; i++) {
        int dr = r4 * 16 + i;
        Vt[((size_t)bh * HD_ + db + dr) * S_ + sb + c] = tile[c][dr];
    }
}

// ---------------- Flash attention (causal), cooperative 4-wave blocks ----------------
// Block = 256 threads (4 waves), covers 64 q-rows of one bh (16 rows/wave).
// K/V tiles (32 keys) staged in double-buffered LDS via global_load_lds:
//   K_lds: [32 keys][256B] XOR-swizzled (byte ^= (row&7)<<4), staged by waves 0-1.
//   V_lds: [128 d][80B pitch] (64B data + 16B pad -> uniform banks), waves 2-3.
// 2-phase pipeline: issue next tile's stage, compute current from LDS, barrier.
__global__ __launch_bounds__(256) void attn_k(const unsigned short* __restrict__ Qr,
                                              const unsigned short* __restrict__ Kr,
                                              const unsigned short* __restrict__ Vt,
                                              unsigned short* __restrict__ attnout) {
    __shared__ __attribute__((aligned(16))) unsigned short Klds[2][4096];  // 8KB each
    __shared__ __attribute__((aligned(16))) unsigned short Vlds[2][5120];  // 10KB each
    __shared__ __attribute__((aligned(16))) unsigned short P[4][16][32];
    int tid = threadIdx.x;
    int w = tid >> 6, lane = tid & 63;
    int lr = lane >> 4, lc = lane & 15;
    int qg = blockIdx.x;
    int bh = blockIdx.y;
    int b = bh >> 4, h = bh & 15;
    int qbase = qg * 64 + w * 16;
    const unsigned short* Qb = Qr + ((size_t)bh * S_ + qbase) * HD_;
    const unsigned short* Kb = Kr + ((size_t)bh * S_) * HD_;
    const unsigned short* Vb = Vt + ((size_t)bh * HD_) * S_;

    s16x8 aq[4];
#pragma unroll
    for (int kc = 0; kc < 4; kc++)
        aq[kc] = *(const s16x8*)(Qb + (size_t)lc * HD_ + kc * 32 + lr * 8);

    float mrow[4], lsum[4];
    f32x4 o[8];
#pragma unroll
    for (int r = 0; r < 4; r++) { mrow[r] = -1e30f; lsum[r] = 0.f; }
#pragma unroll
    for (int dc = 0; dc < 8; dc++) o[dc] = f32x4{0.f, 0.f, 0.f, 0.f};

    auto stage = [&](int kt, int buf) {
        int kb = kt * 32;
        if (w < 2) {  // K tile: 8KB contiguous source, 2 waves x 4 passes x 1KB
            const char* Ksrc = (const char*)(Kb + (size_t)kb * HD_);
            char* Kdst = (char*)&Klds[buf][0];
#pragma unroll
            for (int pass = 0; pass < 4; pass++) {
                int p = (w * 64 + lane) * 16 + pass * 2048;
                int r = p >> 8;
                int c = (p & 255) ^ ((r & 7) << 4);
                gl_lds16(Ksrc + r * 256 + c, Kdst + w * 1024 + pass * 2048);
            }
        } else {  // V tile: 10KB (128 rows x 80B), 2 waves x 5 passes x 1KB
            const char* Vsrc = (const char*)Vb + (size_t)kb * 2;
            char* Vdst = (char*)&Vlds[buf][0];
#pragma unroll
            for (int pass = 0; pass < 5; pass++) {
                int p = ((w - 2) * 64 + lane) * 16 + pass * 2048;
                int r = p / 80;
                int c = p - r * 80;
                if (c >= 64) c = 0;  // pad chunk: harmless duplicate fetch
                gl_lds16(Vsrc + (size_t)r * (S_ * 2) + c, Vdst + (w - 2) * 1024 + pass * 2048);
            }
        }
    };

    int nkt = qg * 2 + 2;  // keys < (qg+1)*64
    const float scale = 0.088388347648318447f;  // 1/sqrt(128)
    int cur = 0;
    stage(0, 0);
    __syncthreads();

    for (int kt = 0; kt < nkt; kt++) {
        if (kt + 1 < nkt) stage(kt + 1, cur ^ 1);
        int kb = kt * 32;
        const char* Kl = (const char*)&Klds[cur][0];
        const char* Vl = (const char*)&Vlds[cur][0];
        f32x4 sf[2];
#pragma unroll
        for (int ct = 0; ct < 2; ct++) {
            f32x4 s4 = f32x4{0.f, 0.f, 0.f, 0.f};
            int rk = ct * 16 + lc;
            const char* Kp = Kl + rk * 256;
            int sw = (rk & 7) << 4;
#pragma unroll
            for (int kc = 0; kc < 4; kc++) {
                s16x8 bk = *(const s16x8*)(Kp + ((kc * 64 + lr * 16) ^ sw));
                s4 = __builtin_amdgcn_mfma_f32_16x16x32_bf16(aq[kc], bk, s4, 0, 0, 0);
            }
            sf[ct] = s4;
        }
        // scale + causal mask
#pragma unroll
        for (int ct = 0; ct < 2; ct++) {
            int key = kb + ct * 16 + lc;
#pragma unroll
            for (int r = 0; r < 4; r++) {
                int qr = qbase + lr * 4 + r;
                float v = sf[ct][r] * scale;
                sf[ct][r] = (key <= qr) ? v : -1e30f;
            }
        }
        // online softmax (16-lane row groups)
        float tmax[4];
#pragma unroll
        for (int r = 0; r < 4; r++) tmax[r] = fmaxf(sf[0][r], sf[1][r]);
#pragma unroll
        for (int off = 1; off < 16; off <<= 1)
#pragma unroll
            for (int r = 0; r < 4; r++)
                tmax[r] = fmaxf(tmax[r], __shfl_xor(tmax[r], off, 64));
        float alpha[4];
#pragma unroll
        for (int r = 0; r < 4; r++) {
            float nm = fmaxf(mrow[r], tmax[r]);
            alpha[r] = __expf(mrow[r] - nm);
            mrow[r] = nm;
        }
        float psum[4] = {0.f, 0.f, 0.f, 0.f};
#pragma unroll
        for (int ct = 0; ct < 2; ct++)
#pragma unroll
            for (int r = 0; r < 4; r++) {
                float p = __expf(sf[ct][r] - mrow[r]);
                sf[ct][r] = p;
                psum[r] += p;
            }
#pragma unroll
        for (int off = 1; off < 16; off <<= 1)
#pragma unroll
            for (int r = 0; r < 4; r++) psum[r] += __shfl_xor(psum[r], off, 64);
#pragma unroll
        for (int r = 0; r < 4; r++) lsum[r] = lsum[r] * alpha[r] + psum[r];
#pragma unroll
        for (int dc = 0; dc < 8; dc++)
#pragma unroll
            for (int r = 0; r < 4; r++) o[dc][r] *= alpha[r];
        // P (D-layout) -> LDS -> A-frag layout (wave-private buffer)
#pragma unroll
        for (int ct = 0; ct < 2; ct++)
#pragma unroll
            for (int r = 0; r < 4; r++) P[w][lr * 4 + r][ct * 16 + lc] = f2bf(sf[ct][r]);
        s16x8 pa = *(const s16x8*)&P[w][lc][lr * 8];
        // PV from V_lds
#pragma unroll
        for (int dc = 0; dc < 8; dc++) {
            int rv = dc * 16 + lc;
            s16x8 bv = *(const s16x8*)(Vl + rv * 80 + lr * 16);
            o[dc] = __builtin_amdgcn_mfma_f32_16x16x32_bf16(pa, bv, o[dc], 0, 0, 0);
        }
        __syncthreads();  // drains next tile's stage + protects buffers
        cur ^= 1;
    }
    // epilogue
#pragma unroll
    for (int dc = 0; dc < 8; dc++)
#pragma unroll
        for (int r = 0; r < 4; r++) {
            int row = qbase + lr * 4 + r;
            int col = h * HD_ + dc * 16 + lc;
            float v = o[dc][r] / lsum[r];
            attnout[((size_t)(b * S_ + row)) * D_ + col] = f2bf(v);
        }
}

extern "C" void kernel_launch(void* const* d_in, const int* in_sizes, int n_in,
                              void* d_out, int out_size, void* d_ws, size_t ws_size,
                              hipStream_t stream) {
    const float* hidden = (const float*)d_in[0];
    // d_in[1]: attention_mask (pure causal; implemented analytically)
    const int* pos_ids = (const int*)d_in[2];  // integer inputs arrive as int32
    const float* Wq = (const float*)d_in[3];
    const float* Wk = (const float*)d_in[4];
    const float* Wv = (const float*)d_in[5];
    const float* Wo = (const float*)d_in[6];
    float* out = (float*)d_out;

    char* ws = (char*)d_ws;
    const size_t MK = (size_t)B_ * S_ * D_;  // 8M elements
    float* cost = (float*)ws;                            // 512KB
    float* sint = (float*)(ws + 524288);                 // 512KB
    unsigned short* qtmp = (unsigned short*)(ws + 1048576);
    unsigned short* ktmp = qtmp + MK;
    unsigned short* vtmp = ktmp + MK;
    unsigned short* Qr = vtmp + MK;
    unsigned short* Kr = Qr + MK;
    unsigned short* Vt = Kr + MK;
    unsigned short* attnout = qtmp;  // reuse (qtmp dead after rope_qk_k)

    const int M = B_ * S_;  // 4096
    dim3 ggrid(D_ / 128, M / 128);  // (16, 32)

    rope_tab_k<<<S_, 64, 0, stream>>>(cost, sint);
    gemm_k<false, true><<<ggrid, 256, 0, stream>>>(hidden, Wq, qtmp, M, D_, D_);
    gemm_k<false, true><<<ggrid, 256, 0, stream>>>(hidden, Wk, ktmp, M, D_, D_);
    gemm_k<false, true><<<ggrid, 256, 0, stream>>>(hidden, Wv, vtmp, M, D_, D_);
    rope_qk_k<<<dim3(S_, B_ * H_), 64, 0, stream>>>(qtmp, ktmp, cost, sint, pos_ids, Qr, Kr);
    vtrans_k<<<dim3(S_ / 64, HD_ / 64, B_ * H_), 256, 0, stream>>>(vtmp, Vt);
    attn_k<<<dim3(S_ / 64, B_ * H_), 256, 0, stream>>>(Qr, Kr, Vt, attnout);
    gemm_k<true, false><<<ggrid, 256, 0, stream>>>(attnout, Wo, out, M, D_, D_);
}

// Round 5
// 606.555 us; speedup vs baseline: 1.9541x; 1.4868x over previous
//
#include <hip/hip_runtime.h>
#include <hip/hip_bf16.h>

#define B_ 2
#define S_ 2048
#define D_ 2048
#define H_ 16
#define HD_ 128

typedef short s16x8 __attribute__((ext_vector_type(8)));
typedef unsigned short u16x8 __attribute__((ext_vector_type(8)));
typedef float f32x4 __attribute__((ext_vector_type(4)));

#define AS1 __attribute__((address_space(1)))
#define AS3 __attribute__((address_space(3)))

__device__ __forceinline__ void gl_lds16(const void* g, void* l) {
    __builtin_amdgcn_global_load_lds((AS1 const unsigned int*)g, (AS3 unsigned int*)l, 16, 0, 0);
}

__device__ inline unsigned short f2bf(float f) {
    __hip_bfloat16 h = __float2bfloat16(f);
    return __builtin_bit_cast(unsigned short, h);
}
__device__ inline float bf2f(unsigned short u) {
    __hip_bfloat16 h = __builtin_bit_cast(__hip_bfloat16, u);
    return __bfloat162float(h);
}

// ---------------- RoPE tables: cos/sin [S][64] fp32 ----------------
__global__ void rope_tab_k(float* __restrict__ cost, float* __restrict__ sint) {
    int s = blockIdx.x;
    int i = threadIdx.x;  // 0..63
    float inv = powf(10000.0f, -((float)(2 * i) / 128.0f));
    float ang = (float)s * inv;
    cost[s * 64 + i] = cosf(ang);
    sint[s * 64 + i] = sinf(ang);
}

// ---------------- fp32 -> bf16 elementwise (8 elems/thread) ----------------
__global__ __launch_bounds__(256) void cvt_f2bf_k(const float* __restrict__ in,
                                                  unsigned short* __restrict__ out) {
    size_t i = ((size_t)blockIdx.x * 256 + threadIdx.x) * 8;
    float4 a = *(const float4*)(in + i);
    float4 b = *(const float4*)(in + i + 4);
    u16x8 o;
    o[0] = f2bf(a.x); o[1] = f2bf(a.y); o[2] = f2bf(a.z); o[3] = f2bf(a.w);
    o[4] = f2bf(b.x); o[5] = f2bf(b.y); o[6] = f2bf(b.z); o[7] = f2bf(b.w);
    *(u16x8*)(out + i) = o;
}

// ---------------- W[K][N] fp32 -> Wt[N][K] bf16 (64x64 LDS tiles) ----------------
__global__ __launch_bounds__(256) void wtrans_k(const float* __restrict__ W,
                                                unsigned short* __restrict__ Wt,
                                                int K, int N) {
    __shared__ unsigned short tile[64][65];
    int kb = blockIdx.x * 64, nb = blockIdx.y * 64;
    int t = threadIdx.x;
    int c = t & 63, r4 = t >> 6;
#pragma unroll
    for (int i = 0; i < 16; i++) {
        int r = r4 * 16 + i;
        tile[r][c] = f2bf(W[(size_t)(kb + r) * N + nb + c]);
    }
    __syncthreads();
#pragma unroll
    for (int i = 0; i < 16; i++) {
        int r = r4 * 16 + i;
        Wt[(size_t)(nb + r) * K + kb + c] = tile[c][r];
    }
}

// ---------------- m97-style GEMM: C[M][N] = A[M][K] * Bt[N][K]^T ----------------
// A, Bt bf16 row-major. 128x128 tile, BK=64, 256 thr (4 waves 2x2), linear LDS,
// global_load_lds width-16 staging, 2 barriers per K-step.
template <bool OUT_BF16>
__global__ __launch_bounds__(256) void gemm_bt_k(const unsigned short* __restrict__ A,
                                                 const unsigned short* __restrict__ Bt,
                                                 void* __restrict__ Cp,
                                                 int M, int N, int K) {
    __shared__ __attribute__((aligned(16))) unsigned short As[128 * 64];
    __shared__ __attribute__((aligned(16))) unsigned short Bs[128 * 64];
    int mbase = blockIdx.y * 128;
    int nbase = blockIdx.x * 128;
    int t = threadIdx.x;
    int w = t >> 6, lane = t & 63;
    int wr = w >> 1, wc = w & 1;
    int lr = lane >> 4, lc = lane & 15;

    f32x4 acc[4][4];
#pragma unroll
    for (int m = 0; m < 4; m++)
#pragma unroll
        for (int n = 0; n < 4; n++) acc[m][n] = f32x4{0.f, 0.f, 0.f, 0.f};

    for (int kb = 0; kb < K; kb += 64) {
        // stage both 16KB tiles: 4 issues x 256 lanes x 16B each
#pragma unroll
        for (int is = 0; is < 4; is++) {
            int p = is * 4096 + t * 16;  // byte offset in tile; row stride 128B
            int row = p >> 7;
            int cb = p & 127;
            gl_lds16((const char*)A + ((size_t)(mbase + row) * K + kb) * 2 + cb,
                     (char*)As + p);
            gl_lds16((const char*)Bt + ((size_t)(nbase + row) * K + kb) * 2 + cb,
                     (char*)Bs + p);
        }
        __syncthreads();
#pragma unroll
        for (int kc = 0; kc < 2; kc++) {
            int ko = kc * 32 + lr * 8;
            s16x8 af[4], bfr[4];
#pragma unroll
            for (int m = 0; m < 4; m++)
                af[m] = *(const s16x8*)&As[(wr * 64 + m * 16 + lc) * 64 + ko];
#pragma unroll
            for (int n = 0; n < 4; n++)
                bfr[n] = *(const s16x8*)&Bs[(wc * 64 + n * 16 + lc) * 64 + ko];
#pragma unroll
            for (int m = 0; m < 4; m++)
#pragma unroll
                for (int n = 0; n < 4; n++)
                    acc[m][n] = __builtin_amdgcn_mfma_f32_16x16x32_bf16(
                        af[m], bfr[n], acc[m][n], 0, 0, 0);
        }
        __syncthreads();
    }
    // epilogue
    int rbase = mbase + wr * 64;
    int cbase = nbase + wc * 64;
#pragma unroll
    for (int m = 0; m < 4; m++)
#pragma unroll
        for (int n = 0; n < 4; n++)
#pragma unroll
            for (int r = 0; r < 4; r++) {
                int row = rbase + m * 16 + lr * 4 + r;
                int col = cbase + n * 16 + lc;
                float v = acc[m][n][r];
                if constexpr (OUT_BF16)
                    ((unsigned short*)Cp)[(size_t)row * N + col] = f2bf(v);
                else
                    ((float*)Cp)[(size_t)row * N + col] = v;
            }
}

// ---------------- RoPE + reshape to [B,H,S,HD] for Q and K ----------------
__global__ void rope_qk_k(const unsigned short* __restrict__ qtmp,
                          const unsigned short* __restrict__ ktmp,
                          const float* __restrict__ cost, const float* __restrict__ sint,
                          const int* __restrict__ pos_ids,
                          unsigned short* __restrict__ Qr, unsigned short* __restrict__ Kr) {
    int s = blockIdx.x;
    int bh = blockIdx.y;
    int b = bh >> 4, h = bh & 15;
    int d = threadIdx.x;  // 0..63
    int pos = pos_ids[(size_t)b * S_ + s];
    float c = cost[pos * 64 + d];
    float sn = sint[pos * 64 + d];
    size_t src = ((size_t)(b * S_ + s)) * D_ + h * HD_ + d;
    float q1 = bf2f(qtmp[src]), q2 = bf2f(qtmp[src + 64]);
    float k1 = bf2f(ktmp[src]), k2 = bf2f(ktmp[src + 64]);
    size_t dst = ((size_t)bh * S_ + s) * HD_ + d;
    Qr[dst] = f2bf(q1 * c - q2 * sn);
    Qr[dst + 64] = f2bf(q2 * c + q1 * sn);
    Kr[dst] = f2bf(k1 * c - k2 * sn);
    Kr[dst + 64] = f2bf(k2 * c + k1 * sn);
}

// ---------------- V transpose: Vt[B,H,HD,S] = V[B,S,H,HD] ----------------
__global__ __launch_bounds__(256) void vtrans_k(const unsigned short* __restrict__ vtmp,
                                                unsigned short* __restrict__ Vt) {
    __shared__ unsigned short tile[64][65];
    int sb = blockIdx.x * 64;
    int db = blockIdx.y * 64;  // 0 or 64
    int bh = blockIdx.z;
    int b = bh >> 4, h = bh & 15;
    int t = threadIdx.x;
    int c = t & 63, r4 = t >> 6;
#pragma unroll
    for (int i = 0; i < 16; i++) {
        int r = r4 * 16 + i;
        tile[r][c] = vtmp[((size_t)(b * S_ + sb + r)) * D_ + h * HD_ + db + c];
    }
    __syncthreads();
#pragma unroll
    for (int i = 0; i < 16; i++) {
        int dr = r4 * 16 + i;
        Vt[((size_t)bh * HD_ + db + dr) * S_ + sb + c] = tile[c][dr];
    }
}

// ---------------- Flash attention (causal), cooperative 4-wave blocks ----------------
__global__ __launch_bounds__(256) void attn_k(const unsigned short* __restrict__ Qr,
                                              const unsigned short* __restrict__ Kr,
                                              const unsigned short* __restrict__ Vt,
                                              unsigned short* __restrict__ attnout) {
    __shared__ __attribute__((aligned(16))) unsigned short Klds[2][4096];  // 8KB each
    __shared__ __attribute__((aligned(16))) unsigned short Vlds[2][5120];  // 10KB each
    __shared__ __attribute__((aligned(16))) unsigned short P[4][16][32];
    int tid = threadIdx.x;
    int w = tid >> 6, lane = tid & 63;
    int lr = lane >> 4, lc = lane & 15;
    int qg = blockIdx.x;
    int bh = blockIdx.y;
    int b = bh >> 4, h = bh & 15;
    int qbase = qg * 64 + w * 16;
    const unsigned short* Qb = Qr + ((size_t)bh * S_ + qbase) * HD_;
    const unsigned short* Kb = Kr + ((size_t)bh * S_) * HD_;
    const unsigned short* Vb = Vt + ((size_t)bh * HD_) * S_;

    s16x8 aq[4];
#pragma unroll
    for (int kc = 0; kc < 4; kc++)
        aq[kc] = *(const s16x8*)(Qb + (size_t)lc * HD_ + kc * 32 + lr * 8);

    float mrow[4], lsum[4];
    f32x4 o[8];
#pragma unroll
    for (int r = 0; r < 4; r++) { mrow[r] = -1e30f; lsum[r] = 0.f; }
#pragma unroll
    for (int dc = 0; dc < 8; dc++) o[dc] = f32x4{0.f, 0.f, 0.f, 0.f};

    auto stage = [&](int kt, int buf) {
        int kb = kt * 32;
        if (w < 2) {  // K tile: 8KB, XOR-swizzled via pre-swizzled global source
            const char* Ksrc = (const char*)(Kb + (size_t)kb * HD_);
            char* Kdst = (char*)&Klds[buf][0];
#pragma unroll
            for (int pass = 0; pass < 4; pass++) {
                int p = (w * 64 + lane) * 16 + pass * 2048;
                int r = p >> 8;
                int c = (p & 255) ^ ((r & 7) << 4);
                gl_lds16(Ksrc + r * 256 + c, Kdst + w * 1024 + pass * 2048);
            }
        } else {  // V tile: 128 rows x 80B pitch (64B data + 16B pad)
            const char* Vsrc = (const char*)Vb + (size_t)kb * 2;
            char* Vdst = (char*)&Vlds[buf][0];
#pragma unroll
            for (int pass = 0; pass < 5; pass++) {
                int p = ((w - 2) * 64 + lane) * 16 + pass * 2048;
                int r = p / 80;
                int c = p - r * 80;
                if (c >= 64) c = 0;  // pad chunk: harmless duplicate fetch
                gl_lds16(Vsrc + (size_t)r * (S_ * 2) + c, Vdst + (w - 2) * 1024 + pass * 2048);
            }
        }
    };

    int nkt = qg * 2 + 2;  // keys < (qg+1)*64
    const float scale = 0.088388347648318447f;  // 1/sqrt(128)
    int cur = 0;
    stage(0, 0);
    __syncthreads();

    for (int kt = 0; kt < nkt; kt++) {
        if (kt + 1 < nkt) stage(kt + 1, cur ^ 1);
        int kb = kt * 32;
        const char* Kl = (const char*)&Klds[cur][0];
        const char* Vl = (const char*)&Vlds[cur][0];
        f32x4 sf[2];
#pragma unroll
        for (int ct = 0; ct < 2; ct++) {
            f32x4 s4 = f32x4{0.f, 0.f, 0.f, 0.f};
            int rk = ct * 16 + lc;
            const char* Kp = Kl + rk * 256;
            int sw = (rk & 7) << 4;
#pragma unroll
            for (int kc = 0; kc < 4; kc++) {
                s16x8 bk = *(const s16x8*)(Kp + ((kc * 64 + lr * 16) ^ sw));
                s4 = __builtin_amdgcn_mfma_f32_16x16x32_bf16(aq[kc], bk, s4, 0, 0, 0);
            }
            sf[ct] = s4;
        }
#pragma unroll
        for (int ct = 0; ct < 2; ct++) {
            int key = kb + ct * 16 + lc;
#pragma unroll
            for (int r = 0; r < 4; r++) {
                int qr = qbase + lr * 4 + r;
                float v = sf[ct][r] * scale;
                sf[ct][r] = (key <= qr) ? v : -1e30f;
            }
        }
        float tmax[4];
#pragma unroll
        for (int r = 0; r < 4; r++) tmax[r] = fmaxf(sf[0][r], sf[1][r]);
#pragma unroll
        for (int off = 1; off < 16; off <<= 1)
#pragma unroll
            for (int r = 0; r < 4; r++)
                tmax[r] = fmaxf(tmax[r], __shfl_xor(tmax[r], off, 64));
        float alpha[4];
#pragma unroll
        for (int r = 0; r < 4; r++) {
            float nm = fmaxf(mrow[r], tmax[r]);
            alpha[r] = __expf(mrow[r] - nm);
            mrow[r] = nm;
        }
        float psum[4] = {0.f, 0.f, 0.f, 0.f};
#pragma unroll
        for (int ct = 0; ct < 2; ct++)
#pragma unroll
            for (int r = 0; r < 4; r++) {
                float p = __expf(sf[ct][r] - mrow[r]);
                sf[ct][r] = p;
                psum[r] += p;
            }
#pragma unroll
        for (int off = 1; off < 16; off <<= 1)
#pragma unroll
            for (int r = 0; r < 4; r++) psum[r] += __shfl_xor(psum[r], off, 64);
#pragma unroll
        for (int r = 0; r < 4; r++) lsum[r] = lsum[r] * alpha[r] + psum[r];
#pragma unroll
        for (int dc = 0; dc < 8; dc++)
#pragma unroll
            for (int r = 0; r < 4; r++) o[dc][r] *= alpha[r];
#pragma unroll
        for (int ct = 0; ct < 2; ct++)
#pragma unroll
            for (int r = 0; r < 4; r++) P[w][lr * 4 + r][ct * 16 + lc] = f2bf(sf[ct][r]);
        s16x8 pa = *(const s16x8*)&P[w][lc][lr * 8];
#pragma unroll
        for (int dc = 0; dc < 8; dc++) {
            int rv = dc * 16 + lc;
            s16x8 bv = *(const s16x8*)(Vl + rv * 80 + lr * 16);
            o[dc] = __builtin_amdgcn_mfma_f32_16x16x32_bf16(pa, bv, o[dc], 0, 0, 0);
        }
        __syncthreads();
        cur ^= 1;
    }
#pragma unroll
    for (int dc = 0; dc < 8; dc++)
#pragma unroll
        for (int r = 0; r < 4; r++) {
            int row = qbase + lr * 4 + r;
            int col = h * HD_ + dc * 16 + lc;
            float v = o[dc][r] / lsum[r];
            attnout[((size_t)(b * S_ + row)) * D_ + col] = f2bf(v);
        }
}

extern "C" void kernel_launch(void* const* d_in, const int* in_sizes, int n_in,
                              void* d_out, int out_size, void* d_ws, size_t ws_size,
                              hipStream_t stream) {
    const float* hidden = (const float*)d_in[0];
    // d_in[1]: attention_mask (pure causal; implemented analytically)
    const int* pos_ids = (const int*)d_in[2];
    const float* Wq = (const float*)d_in[3];
    const float* Wk = (const float*)d_in[4];
    const float* Wv = (const float*)d_in[5];
    const float* Wo = (const float*)d_in[6];
    float* out = (float*)d_out;

    char* ws = (char*)d_ws;
    const size_t MB = 1024 * 1024;
    // layout (97MB total, heavy aliasing — all hazards stream-ordered):
    float* cost = (float*)ws;                      // 512KB
    float* sint = (float*)(ws + 512 * 1024);       // 512KB
    unsigned short* Wo_t = (unsigned short*)(ws + 1 * MB);    // 8MB
    unsigned short* hbf  = (unsigned short*)(ws + 9 * MB);    // 16MB; Qr aliases
    unsigned short* Wq_t = (unsigned short*)(ws + 25 * MB);   // 8MB; Kr aliases 25-41
    unsigned short* Wk_t = (unsigned short*)(ws + 33 * MB);   // 8MB
    unsigned short* Wv_t = (unsigned short*)(ws + 41 * MB);   // 8MB; Vt aliases 41-57
    unsigned short* qtmp = (unsigned short*)(ws + 49 * MB);   // 16MB (lower half under Vt)
    unsigned short* ktmp = (unsigned short*)(ws + 65 * MB);   // 16MB; attnout aliases
    unsigned short* vtmp = (unsigned short*)(ws + 81 * MB);   // 16MB
    unsigned short* Qr = hbf;
    unsigned short* Kr = Wq_t;
    unsigned short* Vt = Wv_t;
    unsigned short* attnout = ktmp;

    const int M = B_ * S_;  // 4096
    dim3 ggrid(D_ / 128, M / 128);   // (16, 32)
    dim3 wgrid(D_ / 64, D_ / 64);    // (32, 32)

    rope_tab_k<<<S_, 64, 0, stream>>>(cost, sint);
    cvt_f2bf_k<<<(M * D_) / (256 * 8), 256, 0, stream>>>(hidden, hbf);
    wtrans_k<<<wgrid, 256, 0, stream>>>(Wq, Wq_t, D_, D_);
    wtrans_k<<<wgrid, 256, 0, stream>>>(Wk, Wk_t, D_, D_);
    wtrans_k<<<wgrid, 256, 0, stream>>>(Wv, Wv_t, D_, D_);
    wtrans_k<<<wgrid, 256, 0, stream>>>(Wo, Wo_t, D_, D_);
    gemm_bt_k<true><<<ggrid, 256, 0, stream>>>(hbf, Wq_t, qtmp, M, D_, D_);
    gemm_bt_k<true><<<ggrid, 256, 0, stream>>>(hbf, Wk_t, ktmp, M, D_, D_);
    gemm_bt_k<true><<<ggrid, 256, 0, stream>>>(hbf, Wv_t, vtmp, M, D_, D_);
    rope_qk_k<<<dim3(S_, B_ * H_), 64, 0, stream>>>(qtmp, ktmp, cost, sint, pos_ids, Qr, Kr);
    vtrans_k<<<dim3(S_ / 64, HD_ / 64, B_ * H_), 256, 0, stream>>>(vtmp, Vt);
    attn_k<<<dim3(S_ / 64, B_ * H_), 256, 0, stream>>>(Qr, Kr, Vt, attnout);
    gemm_bt_k<false><<<ggrid, 256, 0, stream>>>(attnout, Wo_t, out, M, D_, D_);
}

// Round 6
// 600.173 us; speedup vs baseline: 1.9749x; 1.0106x over previous
//
#include <hip/hip_runtime.h>
#include <hip/hip_bf16.h>

#define B_ 2
#define S_ 2048
#define D_ 2048
#define H_ 16
#define HD_ 128

typedef short s16x8 __attribute__((ext_vector_type(8)));
typedef unsigned short u16x8 __attribute__((ext_vector_type(8)));
typedef float f32x4 __attribute__((ext_vector_type(4)));

#define AS1 __attribute__((address_space(1)))
#define AS3 __attribute__((address_space(3)))

__device__ __forceinline__ void gl_lds16(const void* g, void* l) {
    __builtin_amdgcn_global_load_lds((AS1 const unsigned int*)g, (AS3 unsigned int*)l, 16, 0, 0);
}

__device__ inline unsigned short f2bf(float f) {
    __hip_bfloat16 h = __float2bfloat16(f);
    return __builtin_bit_cast(unsigned short, h);
}
__device__ inline float bf2f(unsigned short u) {
    __hip_bfloat16 h = __builtin_bit_cast(__hip_bfloat16, u);
    return __bfloat162float(h);
}

// ---------------- RoPE tables: cos/sin [S][64] fp32 ----------------
__global__ void rope_tab_k(float* __restrict__ cost, float* __restrict__ sint) {
    int s = blockIdx.x;
    int i = threadIdx.x;  // 0..63
    float inv = powf(10000.0f, -((float)(2 * i) / 128.0f));
    float ang = (float)s * inv;
    cost[s * 64 + i] = cosf(ang);
    sint[s * 64 + i] = sinf(ang);
}

// ---------------- fp32 -> bf16 elementwise (8 elems/thread) ----------------
__global__ __launch_bounds__(256) void cvt_f2bf_k(const float* __restrict__ in,
                                                  unsigned short* __restrict__ out) {
    size_t i = ((size_t)blockIdx.x * 256 + threadIdx.x) * 8;
    float4 a = *(const float4*)(in + i);
    float4 b = *(const float4*)(in + i + 4);
    u16x8 o;
    o[0] = f2bf(a.x); o[1] = f2bf(a.y); o[2] = f2bf(a.z); o[3] = f2bf(a.w);
    o[4] = f2bf(b.x); o[5] = f2bf(b.y); o[6] = f2bf(b.z); o[7] = f2bf(b.w);
    *(u16x8*)(out + i) = o;
}

// ---------------- W[K][N] fp32 -> Wt[N][K] bf16 (64x64 LDS tiles) ----------------
__global__ __launch_bounds__(256) void wtrans_k(const float* __restrict__ W,
                                                unsigned short* __restrict__ Wt,
                                                int K, int N) {
    __shared__ unsigned short tile[64][65];
    int kb = blockIdx.x * 64, nb = blockIdx.y * 64;
    int t = threadIdx.x;
    int c = t & 63, r4 = t >> 6;
#pragma unroll
    for (int i = 0; i < 16; i++) {
        int r = r4 * 16 + i;
        tile[r][c] = f2bf(W[(size_t)(kb + r) * N + nb + c]);
    }
    __syncthreads();
#pragma unroll
    for (int i = 0; i < 16; i++) {
        int r = r4 * 16 + i;
        Wt[(size_t)(nb + r) * K + kb + c] = tile[c][r];
    }
}

// ---------------- m97-style GEMM: C[M][N] = A[M][K] * Bt[N][K]^T ----------------
template <bool OUT_BF16>
__global__ __launch_bounds__(256) void gemm_bt_k(const unsigned short* __restrict__ A,
                                                 const unsigned short* __restrict__ Bt,
                                                 void* __restrict__ Cp,
                                                 int M, int N, int K) {
    __shared__ __attribute__((aligned(16))) unsigned short As[128 * 64];
    __shared__ __attribute__((aligned(16))) unsigned short Bs[128 * 64];
    int mbase = blockIdx.y * 128;
    int nbase = blockIdx.x * 128;
    int t = threadIdx.x;
    int w = t >> 6, lane = t & 63;
    int wr = w >> 1, wc = w & 1;
    int lr = lane >> 4, lc = lane & 15;

    f32x4 acc[4][4];
#pragma unroll
    for (int m = 0; m < 4; m++)
#pragma unroll
        for (int n = 0; n < 4; n++) acc[m][n] = f32x4{0.f, 0.f, 0.f, 0.f};

    for (int kb = 0; kb < K; kb += 64) {
#pragma unroll
        for (int is = 0; is < 4; is++) {
            int p = is * 4096 + t * 16;
            int row = p >> 7;
            int cb = p & 127;
            gl_lds16((const char*)A + ((size_t)(mbase + row) * K + kb) * 2 + cb,
                     (char*)As + p);
            gl_lds16((const char*)Bt + ((size_t)(nbase + row) * K + kb) * 2 + cb,
                     (char*)Bs + p);
        }
        __syncthreads();
#pragma unroll
        for (int kc = 0; kc < 2; kc++) {
            int ko = kc * 32 + lr * 8;
            s16x8 af[4], bfr[4];
#pragma unroll
            for (int m = 0; m < 4; m++)
                af[m] = *(const s16x8*)&As[(wr * 64 + m * 16 + lc) * 64 + ko];
#pragma unroll
            for (int n = 0; n < 4; n++)
                bfr[n] = *(const s16x8*)&Bs[(wc * 64 + n * 16 + lc) * 64 + ko];
#pragma unroll
            for (int m = 0; m < 4; m++)
#pragma unroll
                for (int n = 0; n < 4; n++)
                    acc[m][n] = __builtin_amdgcn_mfma_f32_16x16x32_bf16(
                        af[m], bfr[n], acc[m][n], 0, 0, 0);
        }
        __syncthreads();
    }
    int rbase = mbase + wr * 64;
    int cbase = nbase + wc * 64;
#pragma unroll
    for (int m = 0; m < 4; m++)
#pragma unroll
        for (int n = 0; n < 4; n++)
#pragma unroll
            for (int r = 0; r < 4; r++) {
                int row = rbase + m * 16 + lr * 4 + r;
                int col = cbase + n * 16 + lc;
                float v = acc[m][n][r];
                if constexpr (OUT_BF16)
                    ((unsigned short*)Cp)[(size_t)row * N + col] = f2bf(v);
                else
                    ((float*)Cp)[(size_t)row * N + col] = v;
            }
}

// ---------------- RoPE + reshape to [B,H,S,HD] for Q and K ----------------
__global__ void rope_qk_k(const unsigned short* __restrict__ qtmp,
                          const unsigned short* __restrict__ ktmp,
                          const float* __restrict__ cost, const float* __restrict__ sint,
                          const int* __restrict__ pos_ids,
                          unsigned short* __restrict__ Qr, unsigned short* __restrict__ Kr) {
    int s = blockIdx.x;
    int bh = blockIdx.y;
    int b = bh >> 4, h = bh & 15;
    int d = threadIdx.x;  // 0..63
    int pos = pos_ids[(size_t)b * S_ + s];
    float c = cost[pos * 64 + d];
    float sn = sint[pos * 64 + d];
    size_t src = ((size_t)(b * S_ + s)) * D_ + h * HD_ + d;
    float q1 = bf2f(qtmp[src]), q2 = bf2f(qtmp[src + 64]);
    float k1 = bf2f(ktmp[src]), k2 = bf2f(ktmp[src + 64]);
    size_t dst = ((size_t)bh * S_ + s) * HD_ + d;
    Qr[dst] = f2bf(q1 * c - q2 * sn);
    Qr[dst + 64] = f2bf(q2 * c + q1 * sn);
    Kr[dst] = f2bf(k1 * c - k2 * sn);
    Kr[dst + 64] = f2bf(k2 * c + k1 * sn);
}

// ---------------- V transpose: Vt[B,H,HD,S] = V[B,S,H,HD] ----------------
__global__ __launch_bounds__(256) void vtrans_k(const unsigned short* __restrict__ vtmp,
                                                unsigned short* __restrict__ Vt) {
    __shared__ unsigned short tile[64][65];
    int sb = blockIdx.x * 64;
    int db = blockIdx.y * 64;  // 0 or 64
    int bh = blockIdx.z;
    int b = bh >> 4, h = bh & 15;
    int t = threadIdx.x;
    int c = t & 63, r4 = t >> 6;
#pragma unroll
    for (int i = 0; i < 16; i++) {
        int r = r4 * 16 + i;
        tile[r][c] = vtmp[((size_t)(b * S_ + sb + r)) * D_ + h * HD_ + db + c];
    }
    __syncthreads();
#pragma unroll
    for (int i = 0; i < 16; i++) {
        int dr = r4 * 16 + i;
        Vt[((size_t)bh * HD_ + db + dr) * S_ + sb + c] = tile[c][dr];
    }
}

// ---------------- Flash attention (causal) ----------------
// Block = 256 thr (4 waves); block covers 128 q-rows; wave = 32 rows (2 m-tiles).
// KV tile = 64 keys, double-buffered LDS (K XOR-swizzled 256B rows; V 144B pitch).
// Per iteration per wave: 32 QK MFMA + 32 PV MFMA. 1 barrier per 64 keys.
// Block remap: each XCD gets 4 bh (4MB K/V = its L2).
__global__ __launch_bounds__(256) void attn_k(const unsigned short* __restrict__ Qr,
                                              const unsigned short* __restrict__ Kr,
                                              const unsigned short* __restrict__ Vt,
                                              unsigned short* __restrict__ attnout) {
    __shared__ __attribute__((aligned(16))) unsigned short Klds[2][8192];   // 16KB each
    __shared__ __attribute__((aligned(16))) unsigned short Vlds[2][9216];   // 18KB each
    __shared__ __attribute__((aligned(16))) unsigned short P[4][16][72];
    int tid = threadIdx.x;
    int w = tid >> 6, lane = tid & 63;
    int lr = lane >> 4, lc = lane & 15;
    int lin = blockIdx.x;                 // 512 blocks
    int xcd = lin & 7;
    int j = lin >> 3;
    int bh = xcd * 4 + (j & 3);           // 4 bh per XCD -> K/V fits XCD L2
    int qg = j >> 2;                      // 0..15
    int b = bh >> 4, h = bh & 15;
    int qbase = qg * 128;
    int qw = qbase + w * 32;              // wave's first q-row
    const unsigned short* Qb = Qr + ((size_t)bh * S_) * HD_;
    const unsigned short* Kb = Kr + ((size_t)bh * S_) * HD_;
    const unsigned short* Vb = Vt + ((size_t)bh * HD_) * S_;

    s16x8 aq[2][4];
#pragma unroll
    for (int m = 0; m < 2; m++)
#pragma unroll
        for (int kc = 0; kc < 4; kc++)
            aq[m][kc] = *(const s16x8*)(Qb + (size_t)(qw + m * 16 + lc) * HD_ + kc * 32 + lr * 8);

    float mrow[2][4], lsum[2][4];
    f32x4 o[2][8];
#pragma unroll
    for (int m = 0; m < 2; m++)
#pragma unroll
        for (int r = 0; r < 4; r++) { mrow[m][r] = -1e30f; lsum[m][r] = 0.f; }
#pragma unroll
    for (int m = 0; m < 2; m++)
#pragma unroll
        for (int dc = 0; dc < 8; dc++) o[m][dc] = f32x4{0.f, 0.f, 0.f, 0.f};

    auto stage = [&](int kt, int buf) {
        int kb = kt * 64;
        const char* Ksrc = (const char*)(Kb + (size_t)kb * HD_);
        char* Kdst = (char*)&Klds[buf][0];
#pragma unroll
        for (int pass = 0; pass < 4; pass++) {
            int p = pass * 256 + tid;     // 1024 slots x 16B
            int r = p >> 4;
            int c = ((p & 15) * 16) ^ ((r & 7) << 4);
            gl_lds16(Ksrc + r * 256 + c, Kdst + p * 16);
        }
        const char* Vsrc = (const char*)Vb + (size_t)kb * 2;
        char* Vdst = (char*)&Vlds[buf][0];
#pragma unroll
        for (int pass = 0; pass < 5; pass++) {
            int p = pass * 256 + tid;     // 1152 slots x 16B (128 rows x 144B)
            if (p < 1152) {
                int pb = p * 16;
                int r = pb / 144;
                int c = pb - r * 144;
                if (c >= 128) c = 0;      // pad slot: harmless duplicate
                gl_lds16(Vsrc + (size_t)r * (S_ * 2) + c, Vdst + pb);
            }
        }
    };

    int nkt = 2 * qg + 2;
    const float scale = 0.088388347648318447f;  // 1/sqrt(128)
    int cur = 0;
    stage(0, 0);
    __syncthreads();

    for (int kt = 0; kt < nkt; kt++) {
        if (kt + 1 < nkt) stage(kt + 1, cur ^ 1);
        int kb = kt * 64;
        const char* Kl = (const char*)&Klds[cur][0];
        const char* Vl = (const char*)&Vlds[cur][0];
#pragma unroll
        for (int m = 0; m < 2; m++) {
            f32x4 sf[4];
#pragma unroll
            for (int ct = 0; ct < 4; ct++) {
                f32x4 s4 = f32x4{0.f, 0.f, 0.f, 0.f};
                int rk = ct * 16 + lc;
                const char* Kp = Kl + rk * 256;
                int sw = (rk & 7) << 4;
#pragma unroll
                for (int kc = 0; kc < 4; kc++) {
                    s16x8 bk = *(const s16x8*)(Kp + ((kc * 64 + lr * 16) ^ sw));
                    s4 = __builtin_amdgcn_mfma_f32_16x16x32_bf16(aq[m][kc], bk, s4, 0, 0, 0);
                }
                sf[ct] = s4;
            }
            // scale + causal mask
#pragma unroll
            for (int ct = 0; ct < 4; ct++) {
                int key = kb + ct * 16 + lc;
#pragma unroll
                for (int r = 0; r < 4; r++) {
                    int qr = qw + m * 16 + lr * 4 + r;
                    float v = sf[ct][r] * scale;
                    sf[ct][r] = (key <= qr) ? v : -1e30f;
                }
            }
            // online softmax over 64 keys (4 ct regs x 16 lanes)
            float tmax[4];
#pragma unroll
            for (int r = 0; r < 4; r++)
                tmax[r] = fmaxf(fmaxf(sf[0][r], sf[1][r]), fmaxf(sf[2][r], sf[3][r]));
#pragma unroll
            for (int off = 1; off < 16; off <<= 1)
#pragma unroll
                for (int r = 0; r < 4; r++)
                    tmax[r] = fmaxf(tmax[r], __shfl_xor(tmax[r], off, 64));
            float alpha[4];
#pragma unroll
            for (int r = 0; r < 4; r++) {
                float nm = fmaxf(mrow[m][r], tmax[r]);
                alpha[r] = __expf(mrow[m][r] - nm);
                mrow[m][r] = nm;
            }
            float psum[4] = {0.f, 0.f, 0.f, 0.f};
#pragma unroll
            for (int ct = 0; ct < 4; ct++)
#pragma unroll
                for (int r = 0; r < 4; r++) {
                    float p = __expf(sf[ct][r] - mrow[m][r]);
                    sf[ct][r] = p;
                    psum[r] += p;
                }
#pragma unroll
            for (int off = 1; off < 16; off <<= 1)
#pragma unroll
                for (int r = 0; r < 4; r++) psum[r] += __shfl_xor(psum[r], off, 64);
#pragma unroll
            for (int r = 0; r < 4; r++) lsum[m][r] = lsum[m][r] * alpha[r] + psum[r];
#pragma unroll
            for (int dc = 0; dc < 8; dc++)
#pragma unroll
                for (int r = 0; r < 4; r++) o[m][dc][r] *= alpha[r];
            // P (D-layout) -> LDS (144B pitch) -> A-frag
#pragma unroll
            for (int ct = 0; ct < 4; ct++)
#pragma unroll
                for (int r = 0; r < 4; r++) P[w][lr * 4 + r][ct * 16 + lc] = f2bf(sf[ct][r]);
            s16x8 pa[2];
#pragma unroll
            for (int s = 0; s < 2; s++) pa[s] = *(const s16x8*)&P[w][lc][s * 32 + lr * 8];
#pragma unroll
            for (int dc = 0; dc < 8; dc++) {
                const char* Vp = Vl + (dc * 16 + lc) * 144;
#pragma unroll
                for (int s = 0; s < 2; s++) {
                    s16x8 bv = *(const s16x8*)(Vp + s * 64 + lr * 16);
                    o[m][dc] = __builtin_amdgcn_mfma_f32_16x16x32_bf16(pa[s], bv, o[m][dc], 0, 0, 0);
                }
            }
        }
        __syncthreads();
        cur ^= 1;
    }
    // epilogue
#pragma unroll
    for (int m = 0; m < 2; m++)
#pragma unroll
        for (int dc = 0; dc < 8; dc++)
#pragma unroll
            for (int r = 0; r < 4; r++) {
                int row = qw + m * 16 + lr * 4 + r;
                int col = h * HD_ + dc * 16 + lc;
                float v = o[m][dc][r] / lsum[m][r];
                attnout[((size_t)(b * S_ + row)) * D_ + col] = f2bf(v);
            }
}

extern "C" void kernel_launch(void* const* d_in, const int* in_sizes, int n_in,
                              void* d_out, int out_size, void* d_ws, size_t ws_size,
                              hipStream_t stream) {
    const float* hidden = (const float*)d_in[0];
    const int* pos_ids = (const int*)d_in[2];
    const float* Wq = (const float*)d_in[3];
    const float* Wk = (const float*)d_in[4];
    const float* Wv = (const float*)d_in[5];
    const float* Wo = (const float*)d_in[6];
    float* out = (float*)d_out;

    char* ws = (char*)d_ws;
    const size_t MB = 1024 * 1024;
    float* cost = (float*)ws;                      // 512KB
    float* sint = (float*)(ws + 512 * 1024);       // 512KB
    unsigned short* Wo_t = (unsigned short*)(ws + 1 * MB);    // 8MB
    unsigned short* hbf  = (unsigned short*)(ws + 9 * MB);    // 16MB; Qr aliases
    unsigned short* Wq_t = (unsigned short*)(ws + 25 * MB);   // 8MB; Kr aliases 25-41
    unsigned short* Wk_t = (unsigned short*)(ws + 33 * MB);   // 8MB
    unsigned short* Wv_t = (unsigned short*)(ws + 41 * MB);   // 8MB; Vt aliases 41-57
    unsigned short* qtmp = (unsigned short*)(ws + 49 * MB);   // 16MB
    unsigned short* ktmp = (unsigned short*)(ws + 65 * MB);   // 16MB; attnout aliases
    unsigned short* vtmp = (unsigned short*)(ws + 81 * MB);   // 16MB
    unsigned short* Qr = hbf;
    unsigned short* Kr = Wq_t;
    unsigned short* Vt = Wv_t;
    unsigned short* attnout = ktmp;

    const int M = B_ * S_;  // 4096
    dim3 ggrid(D_ / 128, M / 128);   // (16, 32)
    dim3 wgrid(D_ / 64, D_ / 64);    // (32, 32)

    rope_tab_k<<<S_, 64, 0, stream>>>(cost, sint);
    cvt_f2bf_k<<<(M * D_) / (256 * 8), 256, 0, stream>>>(hidden, hbf);
    wtrans_k<<<wgrid, 256, 0, stream>>>(Wq, Wq_t, D_, D_);
    wtrans_k<<<wgrid, 256, 0, stream>>>(Wk, Wk_t, D_, D_);
    wtrans_k<<<wgrid, 256, 0, stream>>>(Wv, Wv_t, D_, D_);
    wtrans_k<<<wgrid, 256, 0, stream>>>(Wo, Wo_t, D_, D_);
    gemm_bt_k<true><<<ggrid, 256, 0, stream>>>(hbf, Wq_t, qtmp, M, D_, D_);
    gemm_bt_k<true><<<ggrid, 256, 0, stream>>>(hbf, Wk_t, ktmp, M, D_, D_);
    gemm_bt_k<true><<<ggrid, 256, 0, stream>>>(hbf, Wv_t, vtmp, M, D_, D_);
    rope_qk_k<<<dim3(S_, B_ * H_), 64, 0, stream>>>(qtmp, ktmp, cost, sint, pos_ids, Qr, Kr);
    vtrans_k<<<dim3(S_ / 64, HD_ / 64, B_ * H_), 256, 0, stream>>>(vtmp, Vt);
    attn_k<<<dim3(512), 256, 0, stream>>>(Qr, Kr, Vt, attnout);
    gemm_bt_k<false><<<ggrid, 256, 0, stream>>>(attnout, Wo_t, out, M, D_, D_);
}

// Round 7
// 499.346 us; speedup vs baseline: 2.3737x; 1.2019x over previous
//
#include <hip/hip_runtime.h>
#include <hip/hip_bf16.h>

#define B_ 2
#define S_ 2048
#define D_ 2048
#define H_ 16
#define HD_ 128

typedef short s16x8 __attribute__((ext_vector_type(8)));
typedef unsigned short u16x8 __attribute__((ext_vector_type(8)));
typedef float f32x4 __attribute__((ext_vector_type(4)));
typedef float f32x16 __attribute__((ext_vector_type(16)));
typedef unsigned int u32x4 __attribute__((ext_vector_type(4)));

#define AS1 __attribute__((address_space(1)))
#define AS3 __attribute__((address_space(3)))

__device__ __forceinline__ void gl_lds16(const void* g, void* l) {
    __builtin_amdgcn_global_load_lds((AS1 const unsigned int*)g, (AS3 unsigned int*)l, 16, 0, 0);
}

__device__ inline unsigned short f2bf(float f) {
    __hip_bfloat16 h = __float2bfloat16(f);
    return __builtin_bit_cast(unsigned short, h);
}
__device__ inline float bf2f(unsigned short u) {
    __hip_bfloat16 h = __builtin_bit_cast(__hip_bfloat16, u);
    return __bfloat162float(h);
}

// ---------------- RoPE tables: cos/sin [S][64] fp32 ----------------
__global__ void rope_tab_k(float* __restrict__ cost, float* __restrict__ sint) {
    int s = blockIdx.x;
    int i = threadIdx.x;  // 0..63
    float inv = powf(10000.0f, -((float)(2 * i) / 128.0f));
    float ang = (float)s * inv;
    cost[s * 64 + i] = cosf(ang);
    sint[s * 64 + i] = sinf(ang);
}

// ---------------- fp32 -> bf16 elementwise (8 elems/thread) ----------------
__global__ __launch_bounds__(256) void cvt_f2bf_k(const float* __restrict__ in,
                                                  unsigned short* __restrict__ out) {
    size_t i = ((size_t)blockIdx.x * 256 + threadIdx.x) * 8;
    float4 a = *(const float4*)(in + i);
    float4 b = *(const float4*)(in + i + 4);
    u16x8 o;
    o[0] = f2bf(a.x); o[1] = f2bf(a.y); o[2] = f2bf(a.z); o[3] = f2bf(a.w);
    o[4] = f2bf(b.x); o[5] = f2bf(b.y); o[6] = f2bf(b.z); o[7] = f2bf(b.w);
    *(u16x8*)(out + i) = o;
}

// ---------------- W[K][N] fp32 -> Wt[N][K] bf16 (64x64 LDS tiles) ----------------
__global__ __launch_bounds__(256) void wtrans_k(const float* __restrict__ W,
                                                unsigned short* __restrict__ Wt,
                                                int K, int N) {
    __shared__ unsigned short tile[64][65];
    int kb = blockIdx.x * 64, nb = blockIdx.y * 64;
    int t = threadIdx.x;
    int c = t & 63, r4 = t >> 6;
#pragma unroll
    for (int i = 0; i < 16; i++) {
        int r = r4 * 16 + i;
        tile[r][c] = f2bf(W[(size_t)(kb + r) * N + nb + c]);
    }
    __syncthreads();
#pragma unroll
    for (int i = 0; i < 16; i++) {
        int r = r4 * 16 + i;
        Wt[(size_t)(nb + r) * K + kb + c] = tile[c][r];
    }
}

// ---------------- m97-style GEMM: C[M][N] = A[M][K] * Bt[N][K]^T ----------------
template <bool OUT_BF16>
__global__ __launch_bounds__(256) void gemm_bt_k(const unsigned short* __restrict__ A,
                                                 const unsigned short* __restrict__ Bt,
                                                 void* __restrict__ Cp,
                                                 int M, int N, int K) {
    __shared__ __attribute__((aligned(16))) unsigned short As[128 * 64];
    __shared__ __attribute__((aligned(16))) unsigned short Bs[128 * 64];
    int mbase = blockIdx.y * 128;
    int nbase = blockIdx.x * 128;
    int t = threadIdx.x;
    int w = t >> 6, lane = t & 63;
    int wr = w >> 1, wc = w & 1;
    int lr = lane >> 4, lc = lane & 15;

    f32x4 acc[4][4];
#pragma unroll
    for (int m = 0; m < 4; m++)
#pragma unroll
        for (int n = 0; n < 4; n++) acc[m][n] = f32x4{0.f, 0.f, 0.f, 0.f};

    for (int kb = 0; kb < K; kb += 64) {
#pragma unroll
        for (int is = 0; is < 4; is++) {
            int p = is * 4096 + t * 16;
            int row = p >> 7;
            int cb = p & 127;
            gl_lds16((const char*)A + ((size_t)(mbase + row) * K + kb) * 2 + cb,
                     (char*)As + p);
            gl_lds16((const char*)Bt + ((size_t)(nbase + row) * K + kb) * 2 + cb,
                     (char*)Bs + p);
        }
        __syncthreads();
#pragma unroll
        for (int kc = 0; kc < 2; kc++) {
            int ko = kc * 32 + lr * 8;
            s16x8 af[4], bfr[4];
#pragma unroll
            for (int m = 0; m < 4; m++)
                af[m] = *(const s16x8*)&As[(wr * 64 + m * 16 + lc) * 64 + ko];
#pragma unroll
            for (int n = 0; n < 4; n++)
                bfr[n] = *(const s16x8*)&Bs[(wc * 64 + n * 16 + lc) * 64 + ko];
#pragma unroll
            for (int m = 0; m < 4; m++)
#pragma unroll
                for (int n = 0; n < 4; n++)
                    acc[m][n] = __builtin_amdgcn_mfma_f32_16x16x32_bf16(
                        af[m], bfr[n], acc[m][n], 0, 0, 0);
        }
        __syncthreads();
    }
    int rbase = mbase + wr * 64;
    int cbase = nbase + wc * 64;
#pragma unroll
    for (int m = 0; m < 4; m++)
#pragma unroll
        for (int n = 0; n < 4; n++)
#pragma unroll
            for (int r = 0; r < 4; r++) {
                int row = rbase + m * 16 + lr * 4 + r;
                int col = cbase + n * 16 + lc;
                float v = acc[m][n][r];
                if constexpr (OUT_BF16)
                    ((unsigned short*)Cp)[(size_t)row * N + col] = f2bf(v);
                else
                    ((float*)Cp)[(size_t)row * N + col] = v;
            }
}

// ---------------- RoPE + reshape (reads fused qkv [M][6144]) ----------------
// Q output is pre-scaled by 1/sqrt(HD) so attention skips the scale multiply.
__global__ void rope_qk_k(const unsigned short* __restrict__ qkv,
                          const float* __restrict__ cost, const float* __restrict__ sint,
                          const int* __restrict__ pos_ids,
                          unsigned short* __restrict__ Qr, unsigned short* __restrict__ Kr) {
    const float QSCALE = 0.088388347648318447f;  // 1/sqrt(128)
    int s = blockIdx.x;
    int bh = blockIdx.y;
    int b = bh >> 4, h = bh & 15;
    int d = threadIdx.x;  // 0..63
    int pos = pos_ids[(size_t)b * S_ + s];
    float c = cost[pos * 64 + d];
    float sn = sint[pos * 64 + d];
    size_t src = ((size_t)(b * S_ + s)) * 6144 + h * HD_ + d;
    float q1 = bf2f(qkv[src]), q2 = bf2f(qkv[src + 64]);
    float k1 = bf2f(qkv[src + 2048]), k2 = bf2f(qkv[src + 2048 + 64]);
    size_t dst = ((size_t)bh * S_ + s) * HD_ + d;
    Qr[dst] = f2bf((q1 * c - q2 * sn) * QSCALE);
    Qr[dst + 64] = f2bf((q2 * c + q1 * sn) * QSCALE);
    Kr[dst] = f2bf(k1 * c - k2 * sn);
    Kr[dst + 64] = f2bf(k2 * c + k1 * sn);
}

// ---------------- V transpose: Vt[B,H,HD,S] from qkv cols 4096.. ----------------
__global__ __launch_bounds__(256) void vtrans_k(const unsigned short* __restrict__ qkv,
                                                unsigned short* __restrict__ Vt) {
    __shared__ unsigned short tile[64][65];
    int sb = blockIdx.x * 64;
    int db = blockIdx.y * 64;  // 0 or 64
    int bh = blockIdx.z;
    int b = bh >> 4, h = bh & 15;
    int t = threadIdx.x;
    int c = t & 63, r4 = t >> 6;
#pragma unroll
    for (int i = 0; i < 16; i++) {
        int r = r4 * 16 + i;
        tile[r][c] = qkv[((size_t)(b * S_ + sb + r)) * 6144 + 4096 + h * HD_ + db + c];
    }
    __syncthreads();
#pragma unroll
    for (int i = 0; i < 16; i++) {
        int dr = r4 * 16 + i;
        Vt[((size_t)bh * HD_ + db + dr) * S_ + sb + c] = tile[c][dr];
    }
}

// ---------------- Flash attention (causal), 32x32 swapped-QK^T ----------------
// Block = 4 waves; wave w of block j owns q-tile qt = ((w+j)&3)*16+j (32 rows) ->
// per-block iterations 49+j (balanced). KV tile = 32 keys, double-buffered LDS:
//   K: [32 keys][256B] XOR-swizzled (pre-swizzled global source).
//   Vt: [128 d][80B pitch] (64B data + 16B pad -> all 32 banks per 8 rows).
// S^T = mfma32(Kfrag, Qfrag): lane owns q-col (lane&31), 16 key-rows in regs ->
// softmax: in-lane reduce + ONE shfl_xor(32); P repack in registers (no LDS P).
// PV: O^T = mfma32(Vt_frag, P); running m,l are single scalars per lane.
__global__ __launch_bounds__(256) void attn32_k(const unsigned short* __restrict__ Qr,
                                                const unsigned short* __restrict__ Kr,
                                                const unsigned short* __restrict__ Vt,
                                                unsigned short* __restrict__ attnout) {
    __shared__ __attribute__((aligned(16))) unsigned short Klds[2][4096];  // 8KB each
    __shared__ __attribute__((aligned(16))) unsigned short Vlds[2][5120];  // 10KB each
    int tid = threadIdx.x;
    int w = tid >> 6, lane = tid & 63;
    int hi = lane >> 5, ln = lane & 31;
    int lin = blockIdx.x;                 // 512 blocks
    int xcd = lin & 7, jj = lin >> 3;
    int bh = xcd * 4 + (jj & 3);          // 4 bh per XCD (K/V fits XCD L2)
    int j = jj >> 2;                      // 0..15
    int b = bh >> 4, h = bh & 15;
    int qt = ((w + j) & 3) * 16 + j;      // strided+rotated q-tile for balance
    int qw = qt * 32;
    int qrow = qw + ln;
    const unsigned short* Kb = Kr + (size_t)bh * S_ * HD_;
    const unsigned short* Vb = Vt + (size_t)bh * HD_ * S_;

    // Q fragments (B-operand): lane ln owns q-column qrow; k-dim = d.
    s16x8 qf[8];
#pragma unroll
    for (int kk = 0; kk < 8; kk++)
        qf[kk] = *(const s16x8*)(Qr + ((size_t)bh * S_ + qrow) * HD_ + kk * 16 + hi * 8);

    f32x16 O[4];
#pragma unroll
    for (int dt = 0; dt < 4; dt++)
#pragma unroll
        for (int r = 0; r < 16; r++) O[dt][r] = 0.f;
    float mrun = -1e30f, lrun = 0.f;

    auto stage = [&](int kt, int buf) {
        int kb = kt * 32;
        const char* Ksrc = (const char*)(Kb + (size_t)kb * HD_);
        char* Kdst = (char*)&Klds[buf][0];
#pragma unroll
        for (int pass = 0; pass < 2; pass++) {
            int p = pass * 256 + tid;     // 512 slots x 16B
            int r = p >> 4;
            int c = ((p & 15) * 16) ^ ((r & 7) << 4);
            gl_lds16(Ksrc + r * 256 + c, Kdst + p * 16);
        }
        const char* Vsrc = (const char*)Vb + (size_t)kb * 2;
        char* Vdst = (char*)&Vlds[buf][0];
#pragma unroll
        for (int pass = 0; pass < 3; pass++) {
            int p = pass * 256 + tid;     // 640 slots x 16B (128 rows x 80B)
            if (p < 640) {
                int r = p / 5, sub = p - r * 5;
                int c = (sub < 4) ? sub * 16 : 0;  // pad slot: harmless dup
                gl_lds16(Vsrc + (size_t)r * (S_ * 2) + c, Vdst + p * 16);
            }
        }
    };

    int nkt = 49 + j;  // block-uniform trip count (max qt = 48+j)
    int cur = 0;
    stage(0, 0);
    __syncthreads();

    for (int kt = 0; kt < nkt; kt++) {
        if (kt + 1 < nkt) stage(kt + 1, cur ^ 1);
        if (kt <= qt) {  // wave-uniform guard
            const char* Kl = (const char*)&Klds[cur][0];
            const char* Vl = (const char*)&Vlds[cur][0];
            // S^T tile: C[key][q], accumulate over d=128 (8 mfma)
            f32x16 p;
#pragma unroll
            for (int r = 0; r < 16; r++) p[r] = 0.f;
            int sw = (ln & 7) << 4;
#pragma unroll
            for (int kk = 0; kk < 8; kk++) {
                s16x8 kf = *(const s16x8*)(Kl + ln * 256 + ((kk * 32 + hi * 16) ^ sw));
                p = __builtin_amdgcn_mfma_f32_32x32x16_bf16(kf, qf[kk], p, 0, 0, 0);
            }
            // causal mask (diagonal tile only): key = kb+krow, q = kb+ln here
            if (kt == qt) {
#pragma unroll
                for (int r = 0; r < 16; r++) {
                    int krow = (r & 3) + 8 * (r >> 2) + 4 * hi;
                    p[r] = (krow <= ln) ? p[r] : -1e30f;
                }
            }
            // online softmax: in-lane over 16 regs + one cross-half exchange
            float tm = p[0];
#pragma unroll
            for (int r = 1; r < 16; r++) tm = fmaxf(tm, p[r]);
            tm = fmaxf(tm, __shfl_xor(tm, 32, 64));
            float nm = fmaxf(mrun, tm);
            float alpha = __expf(mrun - nm);
            mrun = nm;
            float ts = 0.f;
#pragma unroll
            for (int r = 0; r < 16; r++) {
                float e = __expf(p[r] - nm);
                p[r] = e;
                ts += e;
            }
            ts += __shfl_xor(ts, 32, 64);
            lrun = lrun * alpha + ts;
#pragma unroll
            for (int dt = 0; dt < 4; dt++)
#pragma unroll
                for (int r = 0; r < 16; r++) O[dt][r] *= alpha;
            // repack P (C-layout) -> B-fragments in registers
            unsigned int pk[8];
#pragma unroll
            for (int i = 0; i < 8; i++)
                pk[i] = ((unsigned int)f2bf(p[2 * i + 1]) << 16) | f2bf(p[2 * i]);
            unsigned int ex[8];
#pragma unroll
            for (int i = 0; i < 8; i++)
                ex[i] = __shfl_xor(pk[i], 32, 64);
            u32x4 f0 = hi ? u32x4{ex[2], ex[3], pk[2], pk[3]}
                          : u32x4{pk[0], pk[1], ex[0], ex[1]};
            u32x4 f1 = hi ? u32x4{ex[6], ex[7], pk[6], pk[7]}
                          : u32x4{pk[4], pk[5], ex[4], ex[5]};
            s16x8 pb0 = __builtin_bit_cast(s16x8, f0);
            s16x8 pb1 = __builtin_bit_cast(s16x8, f1);
            // PV: O^T[d][q] += V^T_frag x P  (4 d-tiles x 2 k-halves)
#pragma unroll
            for (int dt = 0; dt < 4; dt++) {
                const char* Vp = Vl + (dt * 32 + ln) * 80 + hi * 16;
                s16x8 v0 = *(const s16x8*)(Vp);
                s16x8 v1 = *(const s16x8*)(Vp + 32);
                O[dt] = __builtin_amdgcn_mfma_f32_32x32x16_bf16(v0, pb0, O[dt], 0, 0, 0);
                O[dt] = __builtin_amdgcn_mfma_f32_32x32x16_bf16(v1, pb1, O[dt], 0, 0, 0);
            }
        }
        __syncthreads();
        cur ^= 1;
    }
    // epilogue: attnout[b*S+qrow][h*128 + d]
    float inv = 1.0f / lrun;
#pragma unroll
    for (int dt = 0; dt < 4; dt++)
#pragma unroll
        for (int r = 0; r < 16; r++) {
            int d = dt * 32 + (r & 3) + 8 * (r >> 2) + 4 * hi;
            attnout[((size_t)(b * S_ + qrow)) * D_ + h * HD_ + d] = f2bf(O[dt][r] * inv);
        }
}

extern "C" void kernel_launch(void* const* d_in, const int* in_sizes, int n_in,
                              void* d_out, int out_size, void* d_ws, size_t ws_size,
                              hipStream_t stream) {
    const float* hidden = (const float*)d_in[0];
    const int* pos_ids = (const int*)d_in[2];
    const float* Wq = (const float*)d_in[3];
    const float* Wk = (const float*)d_in[4];
    const float* Wv = (const float*)d_in[5];
    const float* Wo = (const float*)d_in[6];
    float* out = (float*)d_out;

    char* ws = (char*)d_ws;
    const size_t MB = 1024 * 1024;
    float* cost = (float*)ws;                                  // 0.5MB
    float* sint = (float*)(ws + 512 * 1024);                   // 0.5MB
    unsigned short* Wo_t = (unsigned short*)(ws + 1 * MB);     // 8MB
    unsigned short* hbf  = (unsigned short*)(ws + 9 * MB);     // 16MB; Qr aliases
    unsigned short* Wq_t = (unsigned short*)(ws + 25 * MB);    // 8MB; Kr aliases
    unsigned short* Wk_t = (unsigned short*)(ws + 33 * MB);    // 8MB (contiguous w/ Wq_t)
    unsigned short* Wv_t = (unsigned short*)(ws + 41 * MB);    // 8MB; Vt aliases
    unsigned short* qkv  = (unsigned short*)(ws + 49 * MB);    // 48MB; attnout aliases
    unsigned short* Qr = hbf;
    unsigned short* Kr = Wq_t;
    unsigned short* Vt = Wv_t;
    unsigned short* attnout = qkv;

    const int M = B_ * S_;  // 4096
    dim3 qkvgrid(6144 / 128, M / 128);  // (48, 32)
    dim3 ogrid(D_ / 128, M / 128);      // (16, 32)
    dim3 wgrid(D_ / 64, D_ / 64);       // (32, 32)

    rope_tab_k<<<S_, 64, 0, stream>>>(cost, sint);
    cvt_f2bf_k<<<(M * D_) / (256 * 8), 256, 0, stream>>>(hidden, hbf);
    wtrans_k<<<wgrid, 256, 0, stream>>>(Wq, Wq_t, D_, D_);
    wtrans_k<<<wgrid, 256, 0, stream>>>(Wk, Wk_t, D_, D_);
    wtrans_k<<<wgrid, 256, 0, stream>>>(Wv, Wv_t, D_, D_);
    wtrans_k<<<wgrid, 256, 0, stream>>>(Wo, Wo_t, D_, D_);
    // fused QKV projection: Bt rows 0-2047=Wq_t, 2048-4095=Wk_t, 4096-6143=Wv_t
    gemm_bt_k<true><<<qkvgrid, 256, 0, stream>>>(hbf, Wq_t, qkv, M, 6144, D_);
    rope_qk_k<<<dim3(S_, B_ * H_), 64, 0, stream>>>(qkv, cost, sint, pos_ids, Qr, Kr);
    vtrans_k<<<dim3(S_ / 64, HD_ / 64, B_ * H_), 256, 0, stream>>>(qkv, Vt);
    attn32_k<<<dim3(512), 256, 0, stream>>>(Qr, Kr, Vt, attnout);
    gemm_bt_k<false><<<ogrid, 256, 0, stream>>>(attnout, Wo_t, out, M, D_, D_);
}

// Round 10
// 471.076 us; speedup vs baseline: 2.5161x; 1.0600x over previous
//
#include <hip/hip_runtime.h>
#include <hip/hip_bf16.h>

#define B_ 2
#define S_ 2048
#define D_ 2048
#define H_ 16
#define HD_ 128

typedef short s16x8 __attribute__((ext_vector_type(8)));
typedef unsigned short u16x8 __attribute__((ext_vector_type(8)));
typedef float f32x4 __attribute__((ext_vector_type(4)));
typedef float f32x16 __attribute__((ext_vector_type(16)));
typedef unsigned int u32x4 __attribute__((ext_vector_type(4)));

#define AS1 __attribute__((address_space(1)))
#define AS3 __attribute__((address_space(3)))

__device__ __forceinline__ void gl_lds16(const void* g, void* l) {
    __builtin_amdgcn_global_load_lds((AS1 const unsigned int*)g, (AS3 unsigned int*)l, 16, 0, 0);
}

__device__ inline unsigned short f2bf(float f) {
    __hip_bfloat16 h = __float2bfloat16(f);
    return __builtin_bit_cast(unsigned short, h);
}
__device__ inline float bf2f(unsigned short u) {
    __hip_bfloat16 h = __builtin_bit_cast(__hip_bfloat16, u);
    return __bfloat162float(h);
}

// ---------------- RoPE tables: cos/sin [S][64] fp32 ----------------
__global__ void rope_tab_k(float* __restrict__ cost, float* __restrict__ sint) {
    int s = blockIdx.x;
    int i = threadIdx.x;  // 0..63
    float inv = powf(10000.0f, -((float)(2 * i) / 128.0f));
    float ang = (float)s * inv;
    cost[s * 64 + i] = cosf(ang);
    sint[s * 64 + i] = sinf(ang);
}

// ---------------- fp32 -> bf16 elementwise (8 elems/thread) ----------------
__global__ __launch_bounds__(256) void cvt_f2bf_k(const float* __restrict__ in,
                                                  unsigned short* __restrict__ out) {
    size_t i = ((size_t)blockIdx.x * 256 + threadIdx.x) * 8;
    float4 a = *(const float4*)(in + i);
    float4 b = *(const float4*)(in + i + 4);
    u16x8 o;
    o[0] = f2bf(a.x); o[1] = f2bf(a.y); o[2] = f2bf(a.z); o[3] = f2bf(a.w);
    o[4] = f2bf(b.x); o[5] = f2bf(b.y); o[6] = f2bf(b.z); o[7] = f2bf(b.w);
    *(u16x8*)(out + i) = o;
}

// ---------------- W[K][N] fp32 -> Wt[N][K] bf16 (64x64 LDS tiles) ----------------
__global__ __launch_bounds__(256) void wtrans_k(const float* __restrict__ W,
                                                unsigned short* __restrict__ Wt,
                                                int K, int N) {
    __shared__ unsigned short tile[64][65];
    int kb = blockIdx.x * 64, nb = blockIdx.y * 64;
    int t = threadIdx.x;
    int c = t & 63, r4 = t >> 6;
#pragma unroll
    for (int i = 0; i < 16; i++) {
        int r = r4 * 16 + i;
        tile[r][c] = f2bf(W[(size_t)(kb + r) * N + nb + c]);
    }
    __syncthreads();
#pragma unroll
    for (int i = 0; i < 16; i++) {
        int r = r4 * 16 + i;
        Wt[(size_t)(nb + r) * K + kb + c] = tile[c][r];
    }
}

// ---------------- m97-style GEMM + T2 swizzle: C = A * Bt^T ----------------
// LDS tiles [128 rows][64 k] with XOR swizzle: logical byte (row,cb) lives at
// LDS byte (row<<7) + (cb ^ ((row&7)<<4)). Staging keeps LDS dest LINEAR
// (global_load_lds rule) and pre-swizzles the GLOBAL source (involution).
// Fragment ds_read_b128: 16 rows spread over 8 distinct 16B granules -> 2-way.
template <bool OUT_BF16>
__global__ __launch_bounds__(256) void gemm_bt_k(const unsigned short* __restrict__ A,
                                                 const unsigned short* __restrict__ Bt,
                                                 void* __restrict__ Cp,
                                                 int M, int N, int K) {
    __shared__ __attribute__((aligned(16))) unsigned short As[128 * 64];
    __shared__ __attribute__((aligned(16))) unsigned short Bs[128 * 64];
    int mbase = blockIdx.y * 128;
    int nbase = blockIdx.x * 128;
    int t = threadIdx.x;
    int w = t >> 6, lane = t & 63;
    int wr = w >> 1, wc = w & 1;
    int lr = lane >> 4, lc = lane & 15;

    f32x4 acc[4][4];
#pragma unroll
    for (int m = 0; m < 4; m++)
#pragma unroll
        for (int n = 0; n < 4; n++) acc[m][n] = f32x4{0.f, 0.f, 0.f, 0.f};

    for (int kb = 0; kb < K; kb += 64) {
#pragma unroll
        for (int is = 0; is < 4; is++) {
            int p = is * 4096 + t * 16;          // linear LDS byte offset
            int lo = p ^ (((p >> 7) & 7) << 4);  // logical byte offset (involution)
            int row = lo >> 7;
            int cb = lo & 127;
            gl_lds16((const char*)A + ((size_t)(mbase + row) * K + kb) * 2 + cb,
                     (char*)As + p);
            gl_lds16((const char*)Bt + ((size_t)(nbase + row) * K + kb) * 2 + cb,
                     (char*)Bs + p);
        }
        __syncthreads();
#pragma unroll
        for (int kc = 0; kc < 2; kc++) {
            int kob = (kc * 32 + lr * 8) * 2;    // k byte column
            s16x8 af[4], bfr[4];
#pragma unroll
            for (int m = 0; m < 4; m++) {
                int ra = wr * 64 + m * 16 + lc;
                af[m] = *(const s16x8*)((const char*)As + (ra << 7) + (kob ^ ((ra & 7) << 4)));
            }
#pragma unroll
            for (int n = 0; n < 4; n++) {
                int rb = wc * 64 + n * 16 + lc;
                bfr[n] = *(const s16x8*)((const char*)Bs + (rb << 7) + (kob ^ ((rb & 7) << 4)));
            }
#pragma unroll
            for (int m = 0; m < 4; m++)
#pragma unroll
                for (int n = 0; n < 4; n++)
                    acc[m][n] = __builtin_amdgcn_mfma_f32_16x16x32_bf16(
                        af[m], bfr[n], acc[m][n], 0, 0, 0);
        }
        __syncthreads();
    }
    int rbase = mbase + wr * 64;
    int cbase = nbase + wc * 64;
#pragma unroll
    for (int m = 0; m < 4; m++)
#pragma unroll
        for (int n = 0; n < 4; n++)
#pragma unroll
            for (int r = 0; r < 4; r++) {
                int row = rbase + m * 16 + lr * 4 + r;
                int col = cbase + n * 16 + lc;
                float v = acc[m][n][r];
                if constexpr (OUT_BF16)
                    ((unsigned short*)Cp)[(size_t)row * N + col] = f2bf(v);
                else
                    ((float*)Cp)[(size_t)row * N + col] = v;
            }
}

// ---------------- RoPE + reshape (reads fused qkv [M][6144]) ----------------
// Q output is pre-scaled by 1/sqrt(HD) so attention skips the scale multiply.
__global__ void rope_qk_k(const unsigned short* __restrict__ qkv,
                          const float* __restrict__ cost, const float* __restrict__ sint,
                          const int* __restrict__ pos_ids,
                          unsigned short* __restrict__ Qr, unsigned short* __restrict__ Kr) {
    const float QSCALE = 0.088388347648318447f;  // 1/sqrt(128)
    int s = blockIdx.x;
    int bh = blockIdx.y;
    int b = bh >> 4, h = bh & 15;
    int d = threadIdx.x;  // 0..63
    int pos = pos_ids[(size_t)b * S_ + s];
    float c = cost[pos * 64 + d];
    float sn = sint[pos * 64 + d];
    size_t src = ((size_t)(b * S_ + s)) * 6144 + h * HD_ + d;
    float q1 = bf2f(qkv[src]), q2 = bf2f(qkv[src + 64]);
    float k1 = bf2f(qkv[src + 2048]), k2 = bf2f(qkv[src + 2048 + 64]);
    size_t dst = ((size_t)bh * S_ + s) * HD_ + d;
    Qr[dst] = f2bf((q1 * c - q2 * sn) * QSCALE);
    Qr[dst + 64] = f2bf((q2 * c + q1 * sn) * QSCALE);
    Kr[dst] = f2bf(k1 * c - k2 * sn);
    Kr[dst + 64] = f2bf(k2 * c + k1 * sn);
}

// ---------------- V transpose: Vt[B,H,HD,S] from qkv cols 4096.. ----------------
__global__ __launch_bounds__(256) void vtrans_k(const unsigned short* __restrict__ qkv,
                                                unsigned short* __restrict__ Vt) {
    __shared__ unsigned short tile[64][65];
    int sb = blockIdx.x * 64;
    int db = blockIdx.y * 64;  // 0 or 64
    int bh = blockIdx.z;
    int b = bh >> 4, h = bh & 15;
    int t = threadIdx.x;
    int c = t & 63, r4 = t >> 6;
#pragma unroll
    for (int i = 0; i < 16; i++) {
        int r = r4 * 16 + i;
        tile[r][c] = qkv[((size_t)(b * S_ + sb + r)) * 6144 + 4096 + h * HD_ + db + c];
    }
    __syncthreads();
#pragma unroll
    for (int i = 0; i < 16; i++) {
        int dr = r4 * 16 + i;
        Vt[((size_t)bh * HD_ + db + dr) * S_ + sb + c] = tile[c][dr];
    }
}

// ---------------- Flash attention (causal), 32x32 swapped-QK^T ----------------
__global__ __launch_bounds__(256) void attn32_k(const unsigned short* __restrict__ Qr,
                                                const unsigned short* __restrict__ Kr,
                                                const unsigned short* __restrict__ Vt,
                                                unsigned short* __restrict__ attnout) {
    __shared__ __attribute__((aligned(16))) unsigned short Klds[2][4096];  // 8KB each
    __shared__ __attribute__((aligned(16))) unsigned short Vlds[2][5120];  // 10KB each
    int tid = threadIdx.x;
    int w = tid >> 6, lane = tid & 63;
    int hi = lane >> 5, ln = lane & 31;
    int lin = blockIdx.x;                 // 512 blocks
    int xcd = lin & 7, jj = lin >> 3;
    int bh = xcd * 4 + (jj & 3);          // 4 bh per XCD (K/V fits XCD L2)
    int j = jj >> 2;                      // 0..15
    int b = bh >> 4, h = bh & 15;
    int qt = ((w + j) & 3) * 16 + j;      // strided+rotated q-tile for balance
    int qw = qt * 32;
    int qrow = qw + ln;
    const unsigned short* Kb = Kr + (size_t)bh * S_ * HD_;
    const unsigned short* Vb = Vt + (size_t)bh * HD_ * S_;

    // Q fragments (B-operand): lane ln owns q-column qrow; k-dim = d.
    s16x8 qf[8];
#pragma unroll
    for (int kk = 0; kk < 8; kk++)
        qf[kk] = *(const s16x8*)(Qr + ((size_t)bh * S_ + qrow) * HD_ + kk * 16 + hi * 8);

    f32x16 O[4];
#pragma unroll
    for (int dt = 0; dt < 4; dt++)
#pragma unroll
        for (int r = 0; r < 16; r++) O[dt][r] = 0.f;
    float mrun = -1e30f, lrun = 0.f;

    auto stage = [&](int kt, int buf) {
        int kb = kt * 32;
        const char* Ksrc = (const char*)(Kb + (size_t)kb * HD_);
        char* Kdst = (char*)&Klds[buf][0];
#pragma unroll
        for (int pass = 0; pass < 2; pass++) {
            int p = pass * 256 + tid;     // 512 slots x 16B
            int r = p >> 4;
            int c = ((p & 15) * 16) ^ ((r & 7) << 4);
            gl_lds16(Ksrc + r * 256 + c, Kdst + p * 16);
        }
        const char* Vsrc = (const char*)Vb + (size_t)kb * 2;
        char* Vdst = (char*)&Vlds[buf][0];
#pragma unroll
        for (int pass = 0; pass < 3; pass++) {
            int p = pass * 256 + tid;     // 640 slots x 16B (128 rows x 80B)
            if (p < 640) {
                int r = p / 5, sub = p - r * 5;
                int c = (sub < 4) ? sub * 16 : 0;  // pad slot: harmless dup
                gl_lds16(Vsrc + (size_t)r * (S_ * 2) + c, Vdst + p * 16);
            }
        }
    };

    int nkt = 49 + j;  // block-uniform trip count (max qt = 48+j)
    int cur = 0;
    stage(0, 0);
    __syncthreads();

    for (int kt = 0; kt < nkt; kt++) {
        if (kt + 1 < nkt) stage(kt + 1, cur ^ 1);
        if (kt <= qt) {  // wave-uniform guard
            const char* Kl = (const char*)&Klds[cur][0];
            const char* Vl = (const char*)&Vlds[cur][0];
            // S^T tile: C[key][q], accumulate over d=128 (8 mfma)
            f32x16 p;
#pragma unroll
            for (int r = 0; r < 16; r++) p[r] = 0.f;
            int sw = (ln & 7) << 4;
#pragma unroll
            for (int kk = 0; kk < 8; kk++) {
                s16x8 kf = *(const s16x8*)(Kl + ln * 256 + ((kk * 32 + hi * 16) ^ sw));
                p = __builtin_amdgcn_mfma_f32_32x32x16_bf16(kf, qf[kk], p, 0, 0, 0);
            }
            // causal mask (diagonal tile only): key = kb+krow, q = kb+ln here
            if (kt == qt) {
#pragma unroll
                for (int r = 0; r < 16; r++) {
                    int krow = (r & 3) + 8 * (r >> 2) + 4 * hi;
                    p[r] = (krow <= ln) ? p[r] : -1e30f;
                }
            }
            // online softmax: in-lane over 16 regs + one cross-half exchange
            float tm = p[0];
#pragma unroll
            for (int r = 1; r < 16; r++) tm = fmaxf(tm, p[r]);
            tm = fmaxf(tm, __shfl_xor(tm, 32, 64));
            float nm = fmaxf(mrun, tm);
            float alpha = __expf(mrun - nm);
            mrun = nm;
            float ts = 0.f;
#pragma unroll
            for (int r = 0; r < 16; r++) {
                float e = __expf(p[r] - nm);
                p[r] = e;
                ts += e;
            }
            ts += __shfl_xor(ts, 32, 64);
            lrun = lrun * alpha + ts;
#pragma unroll
            for (int dt = 0; dt < 4; dt++)
#pragma unroll
                for (int r = 0; r < 16; r++) O[dt][r] *= alpha;
            // repack P (C-layout) -> B-fragments in registers
            unsigned int pk[8];
#pragma unroll
            for (int i = 0; i < 8; i++)
                pk[i] = ((unsigned int)f2bf(p[2 * i + 1]) << 16) | f2bf(p[2 * i]);
            unsigned int ex[8];
#pragma unroll
            for (int i = 0; i < 8; i++)
                ex[i] = __shfl_xor(pk[i], 32, 64);
            u32x4 f0 = hi ? u32x4{ex[2], ex[3], pk[2], pk[3]}
                          : u32x4{pk[0], pk[1], ex[0], ex[1]};
            u32x4 f1 = hi ? u32x4{ex[6], ex[7], pk[6], pk[7]}
                          : u32x4{pk[4], pk[5], ex[4], ex[5]};
            s16x8 pb0 = __builtin_bit_cast(s16x8, f0);
            s16x8 pb1 = __builtin_bit_cast(s16x8, f1);
            // PV: O^T[d][q] += V^T_frag x P  (4 d-tiles x 2 k-halves)
#pragma unroll
            for (int dt = 0; dt < 4; dt++) {
                const char* Vp = Vl + (dt * 32 + ln) * 80 + hi * 16;
                s16x8 v0 = *(const s16x8*)(Vp);
                s16x8 v1 = *(const s16x8*)(Vp + 32);
                O[dt] = __builtin_amdgcn_mfma_f32_32x32x16_bf16(v0, pb0, O[dt], 0, 0, 0);
                O[dt] = __builtin_amdgcn_mfma_f32_32x32x16_bf16(v1, pb1, O[dt], 0, 0, 0);
            }
        }
        __syncthreads();
        cur ^= 1;
    }
    // epilogue: attnout[b*S+qrow][h*128 + d]
    float inv = 1.0f / lrun;
#pragma unroll
    for (int dt = 0; dt < 4; dt++)
#pragma unroll
        for (int r = 0; r < 16; r++) {
            int d = dt * 32 + (r & 3) + 8 * (r >> 2) + 4 * hi;
            attnout[((size_t)(b * S_ + qrow)) * D_ + h * HD_ + d] = f2bf(O[dt][r] * inv);
        }
}

extern "C" void kernel_launch(void* const* d_in, const int* in_sizes, int n_in,
                              void* d_out, int out_size, void* d_ws, size_t ws_size,
                              hipStream_t stream) {
    const float* hidden = (const float*)d_in[0];
    const int* pos_ids = (const int*)d_in[2];
    const float* Wq = (const float*)d_in[3];
    const float* Wk = (const float*)d_in[4];
    const float* Wv = (const float*)d_in[5];
    const float* Wo = (const float*)d_in[6];
    float* out = (float*)d_out;

    char* ws = (char*)d_ws;
    const size_t MB = 1024 * 1024;
    float* cost = (float*)ws;                                  // 0.5MB
    float* sint = (float*)(ws + 512 * 1024);                   // 0.5MB
    unsigned short* Wo_t = (unsigned short*)(ws + 1 * MB);     // 8MB
    unsigned short* hbf  = (unsigned short*)(ws + 9 * MB);     // 16MB; Qr aliases
    unsigned short* Wq_t = (unsigned short*)(ws + 25 * MB);    // 8MB; Kr aliases
    unsigned short* Wk_t = (unsigned short*)(ws + 33 * MB);    // 8MB (contiguous w/ Wq_t)
    unsigned short* Wv_t = (unsigned short*)(ws + 41 * MB);    // 8MB; Vt aliases
    unsigned short* qkv  = (unsigned short*)(ws + 49 * MB);    // 48MB; attnout aliases
    unsigned short* Qr = hbf;
    unsigned short* Kr = Wq_t;
    unsigned short* Vt = Wv_t;
    unsigned short* attnout = qkv;

    const int M = B_ * S_;  // 4096
    dim3 qkvgrid(6144 / 128, M / 128);  // (48, 32)
    dim3 ogrid(D_ / 128, M / 128);      // (16, 32)
    dim3 wgrid(D_ / 64, D_ / 64);       // (32, 32)

    rope_tab_k<<<S_, 64, 0, stream>>>(cost, sint);
    cvt_f2bf_k<<<(M * D_) / (256 * 8), 256, 0, stream>>>(hidden, hbf);
    wtrans_k<<<wgrid, 256, 0, stream>>>(Wq, Wq_t, D_, D_);
    wtrans_k<<<wgrid, 256, 0, stream>>>(Wk, Wk_t, D_, D_);
    wtrans_k<<<wgrid, 256, 0, stream>>>(Wv, Wv_t, D_, D_);
    wtrans_k<<<wgrid, 256, 0, stream>>>(Wo, Wo_t, D_, D_);
    // fused QKV projection: Bt rows 0-2047=Wq_t, 2048-4095=Wk_t, 4096-6143=Wv_t
    gemm_bt_k<true><<<qkvgrid, 256, 0, stream>>>(hbf, Wq_t, qkv, M, 6144, D_);
    rope_qk_k<<<dim3(S_, B_ * H_), 64, 0, stream>>>(qkv, cost, sint, pos_ids, Qr, Kr);
    vtrans_k<<<dim3(S_ / 64, HD_ / 64, B_ * H_), 256, 0, stream>>>(qkv, Vt);
    attn32_k<<<dim3(512), 256, 0, stream>>>(Qr, Kr, Vt, attnout);
    gemm_bt_k<false><<<ogrid, 256, 0, stream>>>(attnout, Wo_t, out, M, D_, D_);
}

// Round 11
// 441.572 us; speedup vs baseline: 2.6842x; 1.0668x over previous
//
#include <hip/hip_runtime.h>
#include <hip/hip_bf16.h>

#define B_ 2
#define S_ 2048
#define D_ 2048
#define H_ 16
#define HD_ 128

typedef short s16x8 __attribute__((ext_vector_type(8)));
typedef unsigned short u16x8 __attribute__((ext_vector_type(8)));
typedef float f32x4 __attribute__((ext_vector_type(4)));
typedef float f32x16 __attribute__((ext_vector_type(16)));
typedef unsigned int u32x4 __attribute__((ext_vector_type(4)));

#define AS1 __attribute__((address_space(1)))
#define AS3 __attribute__((address_space(3)))

__device__ __forceinline__ void gl_lds16(const void* g, void* l) {
    __builtin_amdgcn_global_load_lds((AS1 const unsigned int*)g, (AS3 unsigned int*)l, 16, 0, 0);
}

__device__ inline unsigned short f2bf(float f) {
    __hip_bfloat16 h = __float2bfloat16(f);
    return __builtin_bit_cast(unsigned short, h);
}
__device__ inline float bf2f(unsigned short u) {
    __hip_bfloat16 h = __builtin_bit_cast(__hip_bfloat16, u);
    return __bfloat162float(h);
}

// ---------------- RoPE tables: cos/sin [S][64] fp32 ----------------
__global__ void rope_tab_k(float* __restrict__ cost, float* __restrict__ sint) {
    int s = blockIdx.x;
    int i = threadIdx.x;  // 0..63
    float inv = powf(10000.0f, -((float)(2 * i) / 128.0f));
    float ang = (float)s * inv;
    cost[s * 64 + i] = cosf(ang);
    sint[s * 64 + i] = sinf(ang);
}

// ---------------- fp32 -> bf16 elementwise (8 elems/thread) ----------------
__global__ __launch_bounds__(256) void cvt_f2bf_k(const float* __restrict__ in,
                                                  unsigned short* __restrict__ out) {
    size_t i = ((size_t)blockIdx.x * 256 + threadIdx.x) * 8;
    float4 a = *(const float4*)(in + i);
    float4 b = *(const float4*)(in + i + 4);
    u16x8 o;
    o[0] = f2bf(a.x); o[1] = f2bf(a.y); o[2] = f2bf(a.z); o[3] = f2bf(a.w);
    o[4] = f2bf(b.x); o[5] = f2bf(b.y); o[6] = f2bf(b.z); o[7] = f2bf(b.w);
    *(u16x8*)(out + i) = o;
}

// ---------------- W[K][N] fp32 -> Wt[N][K] bf16 (64x64 LDS tiles) ----------------
__global__ __launch_bounds__(256) void wtrans_k(const float* __restrict__ W,
                                                unsigned short* __restrict__ Wt,
                                                int K, int N) {
    __shared__ unsigned short tile[64][65];
    int kb = blockIdx.x * 64, nb = blockIdx.y * 64;
    int t = threadIdx.x;
    int c = t & 63, r4 = t >> 6;
#pragma unroll
    for (int i = 0; i < 16; i++) {
        int r = r4 * 16 + i;
        tile[r][c] = f2bf(W[(size_t)(kb + r) * N + nb + c]);
    }
    __syncthreads();
#pragma unroll
    for (int i = 0; i < 16; i++) {
        int r = r4 * 16 + i;
        Wt[(size_t)(nb + r) * K + kb + c] = tile[c][r];
    }
}

// ---------------- m97-style GEMM + T2 swizzle: C = A * Bt^T ----------------
template <bool OUT_BF16>
__global__ __launch_bounds__(256) void gemm_bt_k(const unsigned short* __restrict__ A,
                                                 const unsigned short* __restrict__ Bt,
                                                 void* __restrict__ Cp,
                                                 int M, int N, int K) {
    __shared__ __attribute__((aligned(16))) unsigned short As[128 * 64];
    __shared__ __attribute__((aligned(16))) unsigned short Bs[128 * 64];
    int mbase = blockIdx.y * 128;
    int nbase = blockIdx.x * 128;
    int t = threadIdx.x;
    int w = t >> 6, lane = t & 63;
    int wr = w >> 1, wc = w & 1;
    int lr = lane >> 4, lc = lane & 15;

    f32x4 acc[4][4];
#pragma unroll
    for (int m = 0; m < 4; m++)
#pragma unroll
        for (int n = 0; n < 4; n++) acc[m][n] = f32x4{0.f, 0.f, 0.f, 0.f};

    for (int kb = 0; kb < K; kb += 64) {
#pragma unroll
        for (int is = 0; is < 4; is++) {
            int p = is * 4096 + t * 16;          // linear LDS byte offset
            int lo = p ^ (((p >> 7) & 7) << 4);  // logical byte offset (involution)
            int row = lo >> 7;
            int cb = lo & 127;
            gl_lds16((const char*)A + ((size_t)(mbase + row) * K + kb) * 2 + cb,
                     (char*)As + p);
            gl_lds16((const char*)Bt + ((size_t)(nbase + row) * K + kb) * 2 + cb,
                     (char*)Bs + p);
        }
        __syncthreads();
#pragma unroll
        for (int kc = 0; kc < 2; kc++) {
            int kob = (kc * 32 + lr * 8) * 2;    // k byte column
            s16x8 af[4], bfr[4];
#pragma unroll
            for (int m = 0; m < 4; m++) {
                int ra = wr * 64 + m * 16 + lc;
                af[m] = *(const s16x8*)((const char*)As + (ra << 7) + (kob ^ ((ra & 7) << 4)));
            }
#pragma unroll
            for (int n = 0; n < 4; n++) {
                int rb = wc * 64 + n * 16 + lc;
                bfr[n] = *(const s16x8*)((const char*)Bs + (rb << 7) + (kob ^ ((rb & 7) << 4)));
            }
#pragma unroll
            for (int m = 0; m < 4; m++)
#pragma unroll
                for (int n = 0; n < 4; n++)
                    acc[m][n] = __builtin_amdgcn_mfma_f32_16x16x32_bf16(
                        af[m], bfr[n], acc[m][n], 0, 0, 0);
        }
        __syncthreads();
    }
    int rbase = mbase + wr * 64;
    int cbase = nbase + wc * 64;
#pragma unroll
    for (int m = 0; m < 4; m++)
#pragma unroll
        for (int n = 0; n < 4; n++)
#pragma unroll
            for (int r = 0; r < 4; r++) {
                int row = rbase + m * 16 + lr * 4 + r;
                int col = cbase + n * 16 + lc;
                float v = acc[m][n][r];
                if constexpr (OUT_BF16)
                    ((unsigned short*)Cp)[(size_t)row * N + col] = f2bf(v);
                else
                    ((float*)Cp)[(size_t)row * N + col] = v;
            }
}

// ---------------- RoPE + reshape (reads fused qkv [M][6144]) ----------------
// Q output is pre-scaled by 1/sqrt(HD) so attention skips the scale multiply.
__global__ void rope_qk_k(const unsigned short* __restrict__ qkv,
                          const float* __restrict__ cost, const float* __restrict__ sint,
                          const int* __restrict__ pos_ids,
                          unsigned short* __restrict__ Qr, unsigned short* __restrict__ Kr) {
    const float QSCALE = 0.088388347648318447f;  // 1/sqrt(128)
    int s = blockIdx.x;
    int bh = blockIdx.y;
    int b = bh >> 4, h = bh & 15;
    int d = threadIdx.x;  // 0..63
    int pos = pos_ids[(size_t)b * S_ + s];
    float c = cost[pos * 64 + d];
    float sn = sint[pos * 64 + d];
    size_t src = ((size_t)(b * S_ + s)) * 6144 + h * HD_ + d;
    float q1 = bf2f(qkv[src]), q2 = bf2f(qkv[src + 64]);
    float k1 = bf2f(qkv[src + 2048]), k2 = bf2f(qkv[src + 2048 + 64]);
    size_t dst = ((size_t)bh * S_ + s) * HD_ + d;
    Qr[dst] = f2bf((q1 * c - q2 * sn) * QSCALE);
    Qr[dst + 64] = f2bf((q2 * c + q1 * sn) * QSCALE);
    Kr[dst] = f2bf(k1 * c - k2 * sn);
    Kr[dst + 64] = f2bf(k2 * c + k1 * sn);
}

// ---------------- V transpose: Vt[B,H,HD,S] from qkv cols 4096.. ----------------
__global__ __launch_bounds__(256) void vtrans_k(const unsigned short* __restrict__ qkv,
                                                unsigned short* __restrict__ Vt) {
    __shared__ unsigned short tile[64][65];
    int sb = blockIdx.x * 64;
    int db = blockIdx.y * 64;  // 0 or 64
    int bh = blockIdx.z;
    int b = bh >> 4, h = bh & 15;
    int t = threadIdx.x;
    int c = t & 63, r4 = t >> 6;
#pragma unroll
    for (int i = 0; i < 16; i++) {
        int r = r4 * 16 + i;
        tile[r][c] = qkv[((size_t)(b * S_ + sb + r)) * 6144 + 4096 + h * HD_ + db + c];
    }
    __syncthreads();
#pragma unroll
    for (int i = 0; i < 16; i++) {
        int dr = r4 * 16 + i;
        Vt[((size_t)bh * HD_ + db + dr) * S_ + sb + c] = tile[c][dr];
    }
}

// ---------------- Flash attention (causal), 32x32 swapped-QK^T ----------------
// T13 defer-rescale (THR=8) + pair-balanced j mapping: blocks c and c+256 land
// on the same CU (round-robin model); j = jraw<8 ? jraw : 23-jraw makes their
// iteration counts sum to a constant 113 -> no per-CU tail.
__global__ __launch_bounds__(256) void attn32_k(const unsigned short* __restrict__ Qr,
                                                const unsigned short* __restrict__ Kr,
                                                const unsigned short* __restrict__ Vt,
                                                unsigned short* __restrict__ attnout) {
    __shared__ __attribute__((aligned(16))) unsigned short Klds[2][4096];  // 8KB each
    __shared__ __attribute__((aligned(16))) unsigned short Vlds[2][5120];  // 10KB each
    int tid = threadIdx.x;
    int w = tid >> 6, lane = tid & 63;
    int hi = lane >> 5, ln = lane & 31;
    int lin = blockIdx.x;                 // 512 blocks
    int xcd = lin & 7;
    int sub = (lin >> 3) & 3;
    int bh = xcd * 4 + sub;               // 4 bh per XCD (K/V fits XCD L2)
    int jraw = lin >> 5;                  // 0..15
    int j = (jraw < 8) ? jraw : 23 - jraw;  // pair-balanced (c, c+256 sum to 113)
    int b = bh >> 4, h = bh & 15;
    int qt = ((w + j) & 3) * 16 + j;      // strided+rotated q-tile for balance
    int qw = qt * 32;
    int qrow = qw + ln;
    const unsigned short* Kb = Kr + (size_t)bh * S_ * HD_;
    const unsigned short* Vb = Vt + (size_t)bh * HD_ * S_;

    // Q fragments (B-operand): lane ln owns q-column qrow; k-dim = d.
    s16x8 qf[8];
#pragma unroll
    for (int kk = 0; kk < 8; kk++)
        qf[kk] = *(const s16x8*)(Qr + ((size_t)bh * S_ + qrow) * HD_ + kk * 16 + hi * 8);

    f32x16 O[4];
#pragma unroll
    for (int dt = 0; dt < 4; dt++)
#pragma unroll
        for (int r = 0; r < 16; r++) O[dt][r] = 0.f;
    float mrun = -1e30f, lrun = 0.f;

    auto stage = [&](int kt, int buf) {
        int kb = kt * 32;
        const char* Ksrc = (const char*)(Kb + (size_t)kb * HD_);
        char* Kdst = (char*)&Klds[buf][0];
#pragma unroll
        for (int pass = 0; pass < 2; pass++) {
            int p = pass * 256 + tid;     // 512 slots x 16B
            int r = p >> 4;
            int c = ((p & 15) * 16) ^ ((r & 7) << 4);
            gl_lds16(Ksrc + r * 256 + c, Kdst + p * 16);
        }
        const char* Vsrc = (const char*)Vb + (size_t)kb * 2;
        char* Vdst = (char*)&Vlds[buf][0];
#pragma unroll
        for (int pass = 0; pass < 3; pass++) {
            int p = pass * 256 + tid;     // 640 slots x 16B (128 rows x 80B)
            if (p < 640) {
                int r = p / 5, sub2 = p - r * 5;
                int c = (sub2 < 4) ? sub2 * 16 : 0;  // pad slot: harmless dup
                gl_lds16(Vsrc + (size_t)r * (S_ * 2) + c, Vdst + p * 16);
            }
        }
    };

    int nkt = 49 + j;  // block-uniform trip count (max qt = 48+j)
    int cur = 0;
    stage(0, 0);
    __syncthreads();

    for (int kt = 0; kt < nkt; kt++) {
        if (kt + 1 < nkt) stage(kt + 1, cur ^ 1);
        if (kt <= qt) {  // wave-uniform guard
            const char* Kl = (const char*)&Klds[cur][0];
            const char* Vl = (const char*)&Vlds[cur][0];
            // S^T tile: C[key][q], accumulate over d=128 (8 mfma)
            f32x16 p;
#pragma unroll
            for (int r = 0; r < 16; r++) p[r] = 0.f;
            int sw = (ln & 7) << 4;
#pragma unroll
            for (int kk = 0; kk < 8; kk++) {
                s16x8 kf = *(const s16x8*)(Kl + ln * 256 + ((kk * 32 + hi * 16) ^ sw));
                p = __builtin_amdgcn_mfma_f32_32x32x16_bf16(kf, qf[kk], p, 0, 0, 0);
            }
            // causal mask (diagonal tile only): key = kb+krow, q = kb+ln here
            if (kt == qt) {
#pragma unroll
                for (int r = 0; r < 16; r++) {
                    int krow = (r & 3) + 8 * (r >> 2) + 4 * hi;
                    p[r] = (krow <= ln) ? p[r] : -1e30f;
                }
            }
            // online softmax with T13 defer-rescale (THR=8)
            float tm = p[0];
#pragma unroll
            for (int r = 1; r < 16; r++) tm = fmaxf(tm, p[r]);
            tm = fmaxf(tm, __shfl_xor(tm, 32, 64));
            if (!__all(tm - mrun <= 8.0f)) {   // rescale only when max grew
                float nm = fmaxf(mrun, tm);
                float alpha = __expf(mrun - nm);
                lrun *= alpha;
#pragma unroll
                for (int dt = 0; dt < 4; dt++)
#pragma unroll
                    for (int r = 0; r < 16; r++) O[dt][r] *= alpha;
                mrun = nm;
            }
            float ts = 0.f;
#pragma unroll
            for (int r = 0; r < 16; r++) {
                float e = __expf(p[r] - mrun);  // bounded by e^8 when deferred
                p[r] = e;
                ts += e;
            }
            ts += __shfl_xor(ts, 32, 64);
            lrun += ts;
            // repack P (C-layout) -> B-fragments in registers
            unsigned int pk[8];
#pragma unroll
            for (int i = 0; i < 8; i++)
                pk[i] = ((unsigned int)f2bf(p[2 * i + 1]) << 16) | f2bf(p[2 * i]);
            unsigned int ex[8];
#pragma unroll
            for (int i = 0; i < 8; i++)
                ex[i] = __shfl_xor(pk[i], 32, 64);
            u32x4 f0 = hi ? u32x4{ex[2], ex[3], pk[2], pk[3]}
                          : u32x4{pk[0], pk[1], ex[0], ex[1]};
            u32x4 f1 = hi ? u32x4{ex[6], ex[7], pk[6], pk[7]}
                          : u32x4{pk[4], pk[5], ex[4], ex[5]};
            s16x8 pb0 = __builtin_bit_cast(s16x8, f0);
            s16x8 pb1 = __builtin_bit_cast(s16x8, f1);
            // PV: O^T[d][q] += V^T_frag x P  (4 d-tiles x 2 k-halves)
#pragma unroll
            for (int dt = 0; dt < 4; dt++) {
                const char* Vp = Vl + (dt * 32 + ln) * 80 + hi * 16;
                s16x8 v0 = *(const s16x8*)(Vp);
                s16x8 v1 = *(const s16x8*)(Vp + 32);
                O[dt] = __builtin_amdgcn_mfma_f32_32x32x16_bf16(v0, pb0, O[dt], 0, 0, 0);
                O[dt] = __builtin_amdgcn_mfma_f32_32x32x16_bf16(v1, pb1, O[dt], 0, 0, 0);
            }
        }
        __syncthreads();
        cur ^= 1;
    }
    // epilogue: attnout[b*S+qrow][h*128 + d]
    float inv = 1.0f / lrun;
#pragma unroll
    for (int dt = 0; dt < 4; dt++)
#pragma unroll
        for (int r = 0; r < 16; r++) {
            int d = dt * 32 + (r & 3) + 8 * (r >> 2) + 4 * hi;
            attnout[((size_t)(b * S_ + qrow)) * D_ + h * HD_ + d] = f2bf(O[dt][r] * inv);
        }
}

extern "C" void kernel_launch(void* const* d_in, const int* in_sizes, int n_in,
                              void* d_out, int out_size, void* d_ws, size_t ws_size,
                              hipStream_t stream) {
    const float* hidden = (const float*)d_in[0];
    const int* pos_ids = (const int*)d_in[2];
    const float* Wq = (const float*)d_in[3];
    const float* Wk = (const float*)d_in[4];
    const float* Wv = (const float*)d_in[5];
    const float* Wo = (const float*)d_in[6];
    float* out = (float*)d_out;

    char* ws = (char*)d_ws;
    const size_t MB = 1024 * 1024;
    float* cost = (float*)ws;                                  // 0.5MB
    float* sint = (float*)(ws + 512 * 1024);                   // 0.5MB
    unsigned short* Wo_t = (unsigned short*)(ws + 1 * MB);     // 8MB
    unsigned short* hbf  = (unsigned short*)(ws + 9 * MB);     // 16MB; Qr aliases
    unsigned short* Wq_t = (unsigned short*)(ws + 25 * MB);    // 8MB; Kr aliases
    unsigned short* Wk_t = (unsigned short*)(ws + 33 * MB);    // 8MB (contiguous w/ Wq_t)
    unsigned short* Wv_t = (unsigned short*)(ws + 41 * MB);    // 8MB; Vt aliases
    unsigned short* qkv  = (unsigned short*)(ws + 49 * MB);    // 48MB; attnout aliases
    unsigned short* Qr = hbf;
    unsigned short* Kr = Wq_t;
    unsigned short* Vt = Wv_t;
    unsigned short* attnout = qkv;

    const int M = B_ * S_;  // 4096
    dim3 qkvgrid(6144 / 128, M / 128);  // (48, 32)
    dim3 ogrid(D_ / 128, M / 128);      // (16, 32)
    dim3 wgrid(D_ / 64, D_ / 64);       // (32, 32)

    rope_tab_k<<<S_, 64, 0, stream>>>(cost, sint);
    cvt_f2bf_k<<<(M * D_) / (256 * 8), 256, 0, stream>>>(hidden, hbf);
    wtrans_k<<<wgrid, 256, 0, stream>>>(Wq, Wq_t, D_, D_);
    wtrans_k<<<wgrid, 256, 0, stream>>>(Wk, Wk_t, D_, D_);
    wtrans_k<<<wgrid, 256, 0, stream>>>(Wv, Wv_t, D_, D_);
    wtrans_k<<<wgrid, 256, 0, stream>>>(Wo, Wo_t, D_, D_);
    // fused QKV projection: Bt rows 0-2047=Wq_t, 2048-4095=Wk_t, 4096-6143=Wv_t
    gemm_bt_k<true><<<qkvgrid, 256, 0, stream>>>(hbf, Wq_t, qkv, M, 6144, D_);
    rope_qk_k<<<dim3(S_, B_ * H_), 64, 0, stream>>>(qkv, cost, sint, pos_ids, Qr, Kr);
    vtrans_k<<<dim3(S_ / 64, HD_ / 64, B_ * H_), 256, 0, stream>>>(qkv, Vt);
    attn32_k<<<dim3(512), 256, 0, stream>>>(Qr, Kr, Vt, attnout);
    gemm_bt_k<false><<<ogrid, 256, 0, stream>>>(attnout, Wo_t, out, M, D_, D_);
}